// Round 15
// baseline (886.782 us; speedup 1.0000x reference)
//
#include <hip/hip_runtime.h>
#include <hip/hip_cooperative_groups.h>
#include <math.h>

namespace cg = cooperative_groups;

#define DIN 128
#define DOUT 64

#define BK_SHIFT 7          // 128 cols per bucket
#define BK_COLS 128
#define NBK_STRIDE 1024     // blk_hist row stride
#define CCAP 4096           // max edges per bucket staged in LDS (mean ~2046)

__device__ __forceinline__ float safe_pow(float d, float e) {
    float p = powf(d, e);
    return isinf(p) ? 0.0f : p;
}

__device__ __forceinline__ float dot4(float4 a, float4 b) {
    return a.x * b.x + a.y * b.y + a.z * b.z + a.w * b.w;
}

// fp32 -> bf16 (round-to-nearest-even), as raw ushort
__device__ __forceinline__ unsigned short f32_to_bf16(float f) {
    unsigned bits = __float_as_uint(f);
    unsigned r = (bits + 0x7FFFu + ((bits >> 16) & 1u)) >> 16;
    return (unsigned short)r;
}
__device__ __forceinline__ float bf16_to_f32(unsigned short u) {
    return __uint_as_float((unsigned)u << 16);
}

// ---------------------------------------------------------------------------
// Bjorck device passes (8-block row split; blk = 0..7, 8 rows each).
// B operand SYMMETRIC (rows read as cols). Optional CB = 1.5I - 0.5*C.
// ---------------------------------------------------------------------------
__device__ __forceinline__ void mmd(const float* A, const float* B, float* C,
                                    float* CB, int t, int blk) {
    int c = t & 63;
    int r0 = blk * 8 + (t >> 6) * 2;
    float acc0 = 0.f, acc1 = 0.f;
#pragma unroll
    for (int k4 = 0; k4 < 16; ++k4) {
        float4 b  = *(const float4*)&B[c * 64 + k4 * 4];
        float4 a0 = *(const float4*)&A[r0 * 64 + k4 * 4];
        float4 a1 = *(const float4*)&A[(r0 + 1) * 64 + k4 * 4];
        acc0 += dot4(a0, b);
        acc1 += dot4(a1, b);
    }
    C[r0 * 64 + c] = acc0;
    C[(r0 + 1) * 64 + c] = acc1;
    if (CB != nullptr) {
        CB[r0 * 64 + c]       = ((r0 == c)     ? 1.5f : 0.0f) - 0.5f * acc0;
        CB[(r0 + 1) * 64 + c] = ((r0 + 1 == c) ? 1.5f : 0.0f) - 0.5f * acc1;
    }
}

__device__ __forceinline__ void gramd(const float* W, float* G, int t, int blk) {
    int c = t & 63;
    int r0 = blk * 8 + (t >> 6) * 2;
    float acc0 = 0.f, acc1 = 0.f;
#pragma unroll
    for (int k4 = 0; k4 < 32; ++k4) {
        float4 b  = *(const float4*)&W[c * 128 + k4 * 4];
        float4 a0 = *(const float4*)&W[r0 * 128 + k4 * 4];
        float4 a1 = *(const float4*)&W[(r0 + 1) * 128 + k4 * 4];
        acc0 += dot4(a0, b);
        acc1 += dot4(a1, b);
    }
    G[r0 * 64 + c] = acc0;
    G[(r0 + 1) * 64 + c] = acc1;
}

__device__ __forceinline__ void powerd(const float* gH2, float* gSc, int t) {
    float tr = gH2[t * 65];
#pragma unroll
    for (int d = 1; d < 64; d <<= 1) tr += __shfl_xor(tr, d);
    float inv_tr = 1.0f / tr;
    float4 g4[16];
#pragma unroll
    for (int j4 = 0; j4 < 16; ++j4) {
        float4 v = *(const float4*)&gH2[t * 64 + j4 * 4];
        v.x *= inv_tr; v.y *= inv_tr; v.z *= inv_tr; v.w *= inv_tr;
        g4[j4] = v;
    }
    unsigned h = (unsigned)t * 2654435761u;
    float xv = 0.5f + (float)((h >> 17) & 0x7fff) * (1.0f / 32768.0f);
    float yv = 0.f;
    for (int it = 0; it < 8; ++it) {
        float p0 = 0.f, p1 = 0.f, p2 = 0.f, p3 = 0.f;
#pragma unroll
        for (int j4 = 0; j4 < 16; ++j4) {
            float4 xx;
            xx.x = __shfl(xv, j4 * 4 + 0);
            xx.y = __shfl(xv, j4 * 4 + 1);
            xx.z = __shfl(xv, j4 * 4 + 2);
            xx.w = __shfl(xv, j4 * 4 + 3);
            float dd = dot4(g4[j4], xx);
            if (j4 < 4) p0 += dd; else if (j4 < 8) p1 += dd;
            else if (j4 < 12) p2 += dd; else p3 += dd;
        }
        yv = (p0 + p1) + (p2 + p3);
        if (it < 7) xv = yv;
    }
    float num = xv * yv, den = xv * xv;
#pragma unroll
    for (int d = 1; d < 64; d <<= 1) {
        num += __shfl_xor(num, d);
        den += __shfl_xor(den, d);
    }
    if (t == 0) {
        float lam_h2 = tr * num / den;        // = sigma^8
        float sig = powf(lam_h2, 0.125f);
        gSc[0] = 1.0f / (1.1f * sig);
        gSc[1] = 1.0f / (1.21f * sig * sig);
    }
}

__device__ __forceinline__ void wod(const float* W, const float* P,
                                    const float* gSc, float* Wo, int t, int blk) {
    int c = t & 63;
    int r0 = blk * 8 + (t >> 6) * 2;
    float a00 = 0.f, a01 = 0.f, a10 = 0.f, a11 = 0.f;
#pragma unroll 4
    for (int j = 0; j < 64; ++j) {
        float p0 = P[r0 * 64 + j];
        float p1 = P[(r0 + 1) * 64 + j];
        float w0 = W[j * 128 + c];
        float w1 = W[j * 128 + c + 64];
        a00 += p0 * w0; a01 += p0 * w1;
        a10 += p1 * w0; a11 += p1 * w1;
    }
    float sc = gSc[0];
    Wo[r0 * 128 + c]            = sc * a00;
    Wo[r0 * 128 + c + 64]       = sc * a01;
    Wo[(r0 + 1) * 128 + c]      = sc * a10;
    Wo[(r0 + 1) * 128 + c + 64] = sc * a11;
}

// ---------------------------------------------------------------------------
// Cooperative fused Bjorck chain: 16 blocks x 256. Same pass sequence as the
// proven 15-dispatch version; launch boundaries replaced by grid.sync().
// S layout (float offsets): gG 0, gT 4096, gA 8192, gAn 12288, gA0 16384,
// gP 20480, gPn 24576, gB0 28672, gB1 32768, gB2 36864, gB3 40960,
// gB4 45056, gSc 49152.
// ---------------------------------------------------------------------------
__global__ __launch_bounds__(256) void bjorck_coop(const float* __restrict__ W,
                                                   float* __restrict__ S,
                                                   float* __restrict__ Wo) {
    cg::grid_group g = cg::this_grid();
    int t = threadIdx.x;
    int b16 = blockIdx.x;
    bool second = (b16 >= 8);
    int blk = b16 & 7;
    float* gG  = S;          float* gT  = S + 4096;  float* gA  = S + 8192;
    float* gAn = S + 12288;  float* gA0 = S + 16384; float* gP  = S + 20480;
    float* gPn = S + 24576;  float* gB0 = S + 28672; float* gB1 = S + 32768;
    float* gB2 = S + 36864;  float* gB3 = S + 40960; float* gB4 = S + 45056;
    float* gSc = S + 49152;

    if (!second) gramd(W, gG, t, blk);                          // G
    __threadfence(); g.sync();
    if (!second) mmd(gG, gG, gT, nullptr, t, blk);              // H = G^2
    __threadfence(); g.sync();
    if (!second) mmd(gT, gT, gA, nullptr, t, blk);              // H2 = G^4
    __threadfence(); g.sync();
    if (b16 == 0 && t < 64) powerd(gA, gSc, t);                 // sc, rs
    __threadfence(); g.sync();
    {   // prep: A0 = rs*G, B0 = 1.5I - 0.5*A0 (4096 elems over 4096 threads)
        int idx = b16 * 256 + t;
        if (idx < 4096) {
            float rs = gSc[1];
            int r = idx >> 6, c2 = idx & 63;
            float a0 = rs * gG[idx];
            gA0[idx] = a0;
            gB0[idx] = ((r == c2) ? 1.5f : 0.0f) - 0.5f * a0;
        }
    }
    __threadfence(); g.sync();
    if (!second) mmd(gA0, gB0, gT, nullptr, t, blk);            // T = A0@B0
    __threadfence(); g.sync();
    if (!second) mmd(gT, gB0, gA, gB1, t, blk);                 // A1 (+B1)
    __threadfence(); g.sync();
    mmd(second ? gA : gB0, gB1, second ? gT : gP, nullptr, t, blk); // P=B0B1, T=A1B1
    __threadfence(); g.sync();
    if (!second) mmd(gT, gB1, gAn, gB2, t, blk);                // A2 (+B2)
    __threadfence(); g.sync();
    mmd(second ? gAn : gP, gB2, second ? gT : gPn, nullptr, t, blk); // Pn=PB2, T=A2B2
    __threadfence(); g.sync();
    if (!second) mmd(gT, gB2, gA, gB3, t, blk);                 // A3 (+B3)
    __threadfence(); g.sync();
    mmd(second ? gA : gPn, gB3, second ? gT : gP, nullptr, t, blk);  // P=PnB3, T=A3B3
    __threadfence(); g.sync();
    if (!second) mmd(gT, gB3, gAn, gB4, t, blk);                // A4 (+B4)
    __threadfence(); g.sync();
    if (!second) mmd(gP, gB4, gPn, nullptr, t, blk);            // P final
    __threadfence(); g.sync();
    if (!second) wod(W, gPn, gSc, Wo, t, blk);                  // Wo
}

// ---------------------------------------------------------------------------
// per-node prep
// ---------------------------------------------------------------------------
__global__ void node_prep(const float* __restrict__ diags,
                          const float* m1, const float* m2, const float* m3,
                          const float* e1, const float* e2, const float* e3,
                          float* __restrict__ d_e2m, float* __restrict__ d_e3p,
                          float* __restrict__ gso2, int n) {
    int i = blockIdx.x * blockDim.x + threadIdx.x;
    if (i >= n) return;
    float d = diags[i];
    float p1 = safe_pow(d, e1[0]);
    float p2 = safe_pow(d, e2[0]);
    float p3 = safe_pow(d, e3[0]);
    float vm2 = m2[0];
    d_e2m[i] = vm2 * p2;
    d_e3p[i] = p3;
    gso2[i] = m1[0] * p1 + vm2 * p2 * p3 + m3[0];
}

// ---------------------------------------------------------------------------
// xw = x @ Wo^T — register-tiled GEMM; OUTPUT IN BF16.
// ---------------------------------------------------------------------------
#define XN 64
#define XS 132
__global__ __launch_bounds__(256) void xw_kernel(const float* __restrict__ x,
                                                 const float* __restrict__ Wo,
                                                 unsigned short* __restrict__ xwb,
                                                 int n) {
    __shared__ __align__(16) float xs[XN * XS];
    __shared__ __align__(16) float ws[DOUT * XS];
    int t = threadIdx.x;
    int base = blockIdx.x * XN;
    for (int f = t; f < DOUT * (DIN / 4); f += 256) {
        int r = f >> 5, c = f & 31;
        *(float4*)&ws[r * XS + c * 4] = *(const float4*)&Wo[r * DIN + c * 4];
    }
    for (int f = t; f < XN * (DIN / 4); f += 256) {
        int r = f >> 5, c = f & 31;
        int node = base + r;
        float4 v = make_float4(0.f, 0.f, 0.f, 0.f);
        if (node < n) v = *(const float4*)&x[(size_t)node * DIN + c * 4];
        *(float4*)&xs[r * XS + c * 4] = v;
    }
    __syncthreads();
    int tn = t >> 4;
    int td = t & 15;
    float acc[4][4] = {};
#pragma unroll 2
    for (int k4 = 0; k4 < DIN / 4; ++k4) {
        float4 a[4], w[4];
#pragma unroll
        for (int r = 0; r < 4; ++r) a[r] = *(const float4*)&xs[(tn * 4 + r) * XS + k4 * 4];
#pragma unroll
        for (int c = 0; c < 4; ++c) w[c] = *(const float4*)&ws[(td + c * 16) * XS + k4 * 4];
#pragma unroll
        for (int r = 0; r < 4; ++r)
#pragma unroll
            for (int c = 0; c < 4; ++c) acc[r][c] += dot4(a[r], w[c]);
    }
#pragma unroll
    for (int r = 0; r < 4; ++r) {
        int node = base + tn * 4 + r;
        if (node >= n) break;
#pragma unroll
        for (int c = 0; c < 4; ++c)
            xwb[(size_t)node * DOUT + td + c * 16] = f32_to_bf16(acc[r][c]);
    }
}

// ---------------------------------------------------------------------------
// Cooperative fused sort chain: hist -> column scan -> bucket scan ->
// scatter -> per-bucket CSR (+weights). Grid = nbk blocks (one per bucket),
// each block also owns one edge chunk for the hist/scatter phases.
// ---------------------------------------------------------------------------
__global__ __launch_bounds__(256) void sort_coop(const int* __restrict__ ei,
                                                 const float* __restrict__ d_e2m,
                                                 unsigned* __restrict__ blk_hist,
                                                 unsigned* __restrict__ btot,
                                                 unsigned* __restrict__ boff,
                                                 unsigned* __restrict__ bucketed,
                                                 int* __restrict__ offsets,
                                                 uint2* __restrict__ pairs,
                                                 int n, int e_cnt, int nbk, int chunk) {
    cg::grid_group g = cg::this_grid();
    __shared__ int h[NBK_STRIDE];       // hist, later cursors
    __shared__ unsigned sE[CCAP];
    __shared__ int sh2[256];
    __shared__ int shc[BK_COLS], scc[BK_COLS], posc[BK_COLS];
    int b = blockIdx.x, t = threadIdx.x;
    int lo = b * chunk, hi = min(lo + chunk, e_cnt);

    // Phase A: per-chunk bucket histogram
    for (int j = t; j < NBK_STRIDE; j += 256) h[j] = 0;
    __syncthreads();
    for (int e = lo + t; e < hi; e += 256)
        atomicAdd(&h[ei[e_cnt + e] >> BK_SHIFT], 1);
    __syncthreads();
    for (int j = t; j < nbk; j += 256)
        blk_hist[(size_t)b * NBK_STRIDE + j] = (unsigned)h[j];
    __threadfence(); g.sync();

    // Phase B: block b scans bucket b's column over all chunk-rows
    {
        int base = t * 4;
        int v[4];
        int s = 0;
#pragma unroll
        for (int k = 0; k < 4; ++k) {
            int bb = base + k;
            v[k] = (bb < nbk) ? (int)blk_hist[(size_t)bb * NBK_STRIDE + b] : 0;
            s += v[k];
        }
        sh2[t] = s;
        __syncthreads();
        for (int d = 1; d < 256; d <<= 1) {
            int u = (t >= d) ? sh2[t - d] : 0;
            __syncthreads();
            sh2[t] += u;
            __syncthreads();
        }
        int run = sh2[t] - s;
#pragma unroll
        for (int k = 0; k < 4; ++k) {
            int bb = base + k;
            if (bb < nbk) blk_hist[(size_t)bb * NBK_STRIDE + b] = (unsigned)run;
            run += v[k];
        }
        if (t == 255) btot[b] = (unsigned)sh2[255];
    }
    __threadfence(); g.sync();

    // Phase C: block 0 scans bucket totals -> boff
    if (b == 0) {
        int base = t * 4;
        int v[4];
        int s = 0;
#pragma unroll
        for (int k = 0; k < 4; ++k) {
            int j = base + k;
            v[k] = (j < nbk) ? (int)btot[j] : 0;
            s += v[k];
        }
        sh2[t] = s;
        __syncthreads();
        for (int d = 1; d < 256; d <<= 1) {
            int u = (t >= d) ? sh2[t - d] : 0;
            __syncthreads();
            sh2[t] += u;
            __syncthreads();
        }
        int run = sh2[t] - s;
#pragma unroll
        for (int k = 0; k < 4; ++k) {
            int j = base + k;
            if (j < nbk) boff[j] = (unsigned)run;
            run += v[k];
        }
        if (t == 0) boff[nbk] = (unsigned)e_cnt;
    }
    __threadfence(); g.sync();

    // Phase D: scatter packed keys into reserved runs
    for (int j = t; j < nbk; j += 256)
        h[j] = (int)(boff[j] + blk_hist[(size_t)b * NBK_STRIDE + j]);
    __syncthreads();
    for (int e = lo + t; e < hi; e += 256) {
        int col = ei[e_cnt + e];
        int src = ei[e];
        int pos = atomicAdd(&h[col >> BK_SHIFT], 1);
        bucketed[pos] = ((unsigned)src << BK_SHIFT) | (unsigned)(col & (BK_COLS - 1));
    }
    __threadfence(); g.sync();

    // Phase E: per-bucket exact CSR + (src, weight) pairs
    {
        int base2 = (int)boff[b];
        int cnt = (int)boff[b + 1] - base2;
        bool fits = (cnt <= CCAP);
        if (fits)
            for (int i = t; i < cnt; i += 256) sE[i] = bucketed[base2 + i];
        if (t < BK_COLS) shc[t] = 0;
        __syncthreads();
        for (int i = t; i < cnt; i += 256) {
            unsigned p = fits ? sE[i] : bucketed[base2 + i];
            atomicAdd(&shc[p & (BK_COLS - 1)], 1);
        }
        __syncthreads();
        if (t < BK_COLS) scc[t] = shc[t];
        __syncthreads();
        for (int d = 1; d < BK_COLS; d <<= 1) {
            int u = 0;
            if (t < BK_COLS && t >= d) u = scc[t - d];
            __syncthreads();
            if (t < BK_COLS) scc[t] += u;
            __syncthreads();
        }
        if (t < BK_COLS) {
            int pre = scc[t] - shc[t];
            int gc = b * BK_COLS + t;
            if (gc < n) offsets[gc] = base2 + pre;
            posc[t] = pre;
        }
        if (b == 0 && t == 0) offsets[n] = e_cnt;
        __syncthreads();
        for (int i = t; i < cnt; i += 256) {
            unsigned p = fits ? sE[i] : bucketed[base2 + i];
            int lc = (int)(p & (BK_COLS - 1));
            unsigned s = p >> BK_SHIFT;
            int q = atomicAdd(&posc[lc], 1);
            uint2 o;
            o.x = s;
            o.y = __float_as_uint(d_e2m[s]);
            pairs[base2 + q] = o;
        }
    }
}

// ---------------------------------------------------------------------------
// fused gather + self-loop + bias + log-softmax; one wave per node.
// (round-12 version — best measured)
// ---------------------------------------------------------------------------
__global__ __launch_bounds__(256) void gather_kernel(const int* __restrict__ offsets,
                                                     const uint2* __restrict__ pairs,
                                                     const float* __restrict__ d_e3p,
                                                     const unsigned short* __restrict__ xwb,
                                                     const float* __restrict__ gso2,
                                                     const float* __restrict__ b,
                                                     float* __restrict__ out, int n) {
    unsigned lane = threadIdx.x & 63;
    int node = blockIdx.x * 4 + (threadIdx.x >> 6);
    if (node >= n) return;
    int lo = offsets[node], hi = offsets[node + 1];
    float xself = bf16_to_f32(xwb[(size_t)node * DOUT + lane]);
    float v = gso2[node] * xself + 2.0f * b[lane];
    float dn = d_e3p[node];
    float accA = 0.f, accB = 0.f;
    int i = lo;
    for (; i + 8 <= hi; i += 8) {
        uint2 p0 = pairs[i + 0], p1 = pairs[i + 1], p2 = pairs[i + 2], p3 = pairs[i + 3];
        uint2 p4 = pairs[i + 4], p5 = pairs[i + 5], p6 = pairs[i + 6], p7 = pairs[i + 7];
        float a0 = bf16_to_f32(xwb[p0.x * 64u + lane]);
        float a1 = bf16_to_f32(xwb[p1.x * 64u + lane]);
        float a2 = bf16_to_f32(xwb[p2.x * 64u + lane]);
        float a3 = bf16_to_f32(xwb[p3.x * 64u + lane]);
        float a4 = bf16_to_f32(xwb[p4.x * 64u + lane]);
        float a5 = bf16_to_f32(xwb[p5.x * 64u + lane]);
        float a6 = bf16_to_f32(xwb[p6.x * 64u + lane]);
        float a7 = bf16_to_f32(xwb[p7.x * 64u + lane]);
        accA += __uint_as_float(p0.y) * a0 + __uint_as_float(p1.y) * a1
              + __uint_as_float(p2.y) * a2 + __uint_as_float(p3.y) * a3;
        accB += __uint_as_float(p4.y) * a4 + __uint_as_float(p5.y) * a5
              + __uint_as_float(p6.y) * a6 + __uint_as_float(p7.y) * a7;
    }
    for (; i + 2 <= hi; i += 2) {
        uint2 p0 = pairs[i + 0], p1 = pairs[i + 1];
        float a0 = bf16_to_f32(xwb[p0.x * 64u + lane]);
        float a1 = bf16_to_f32(xwb[p1.x * 64u + lane]);
        accA += __uint_as_float(p0.y) * a0;
        accB += __uint_as_float(p1.y) * a1;
    }
    if (i < hi) {
        uint2 p = pairs[i];
        accA += __uint_as_float(p.y) * bf16_to_f32(xwb[p.x * 64u + lane]);
    }
    v += dn * (accA + accB);
    float m = v;
#pragma unroll
    for (int d = 1; d < 64; d <<= 1) m = fmaxf(m, __shfl_xor(m, d));
    float s = expf(v - m);
#pragma unroll
    for (int d = 1; d < 64; d <<= 1) s += __shfl_xor(s, d);
    out[(size_t)node * DOUT + lane] = v - m - logf(s);
}

// ---------------------------------------------------------------------------
extern "C" void kernel_launch(void* const* d_in, const int* in_sizes, int n_in,
                              void* d_out, int out_size, void* d_ws, size_t ws_size,
                              hipStream_t stream) {
    const float* x     = (const float*)d_in[0];
    const int*   ei    = (const int*)d_in[1];
    const float* diags = (const float*)d_in[3];
    const float* W     = (const float*)d_in[4];
    const float* b     = (const float*)d_in[5];
    const float* m1    = (const float*)d_in[6];
    const float* m2    = (const float*)d_in[7];
    const float* m3    = (const float*)d_in[8];
    const float* e1    = (const float*)d_in[9];
    const float* e2    = (const float*)d_in[10];
    const float* e3    = (const float*)d_in[11];
    float* out = (float*)d_out;

    const int n = in_sizes[3];            // 100000
    const int e_cnt = in_sizes[1] / 2;    // 1600000
    const int nbk = (n + BK_COLS - 1) >> BK_SHIFT;          // 782 buckets
    const int chunk = (e_cnt + nbk - 1) / nbk;              // ~2047 edges/block

    char* ws = (char*)d_ws;
    // --- small-matrix region (fixed offsets) ---
    float*    Wo   = (float*)ws;                 // 8192 floats = 32KB
    float*    S    = (float*)(ws + 32768);       // bjorck scratch: 13x4096 f
    // --- big arrays ---
    float*          d_e2m    = S + 53248;              // n
    float*          d_e3p    = d_e2m + n;              // n
    float*          gso2     = d_e3p + n;              // n
    unsigned short* xwb      = (unsigned short*)(gso2 + n);   // n*64 bf16
    int*            offsets  = (int*)(xwb + (size_t)n * DOUT); // n+4
    unsigned*       bucketed = (unsigned*)(offsets + n + 4);   // e_cnt
    unsigned*       blk_hist = bucketed + e_cnt;               // nbk*1024
    unsigned*       btot     = blk_hist + (size_t)nbk * NBK_STRIDE; // 1024
    unsigned*       boff     = btot + 1024;                    // nbk+8
    uintptr_t pp = ((uintptr_t)(boff + nbk + 8) + 15) & ~(uintptr_t)15;
    uint2*          pairs    = (uint2*)pp;                     // e_cnt (8B)

    // ---- Bjorck chain: ONE cooperative kernel ------------------------------
    {
        void* args[] = { (void*)&W, (void*)&S, (void*)&Wo };
        hipLaunchCooperativeKernel((const void*)bjorck_coop, dim3(16), dim3(256),
                                   args, 0, stream);
    }
    // ---- node prep + feature transform ------------------------------------
    node_prep<<<(n + 255) / 256, 256, 0, stream>>>(diags, m1, m2, m3, e1, e2, e3,
                                                   d_e2m, d_e3p, gso2, n);
    xw_kernel<<<(n + XN - 1) / XN, 256, 0, stream>>>(x, Wo, xwb, n);
    // ---- sort chain: ONE cooperative kernel --------------------------------
    {
        int n_ = n, e_ = e_cnt, nbk_ = nbk, ch_ = chunk;
        void* args[] = { (void*)&ei, (void*)&d_e2m, (void*)&blk_hist, (void*)&btot,
                         (void*)&boff, (void*)&bucketed, (void*)&offsets,
                         (void*)&pairs, (void*)&n_, (void*)&e_, (void*)&nbk_,
                         (void*)&ch_ };
        hipLaunchCooperativeKernel((const void*)sort_coop, dim3(nbk), dim3(256),
                                   args, 0, stream);
    }
    // ---- fused gather + softmax --------------------------------------------
    gather_kernel<<<(n + 3) / 4, 256, 0, stream>>>(offsets, pairs, d_e3p,
                                                   xwb, gso2, b, out, n);
}

// Round 16
// 873.545 us; speedup vs baseline: 1.0152x; 1.0152x over previous
//
#include <hip/hip_runtime.h>
#include <hip/hip_cooperative_groups.h>
#include <math.h>

namespace cg = cooperative_groups;

#define DIN 128
#define DOUT 64

#define NCHK 64             // edge chunks for hist/scatter (write locality!)
#define BK_SHIFT 7          // 128 cols per bucket
#define BK_COLS 128
#define NBK_STRIDE 1024     // blk_hist row stride
#define CCAP 4096           // max edges per bucket staged in LDS (mean ~2046)

__device__ __forceinline__ float safe_pow(float d, float e) {
    float p = powf(d, e);
    return isinf(p) ? 0.0f : p;
}

__device__ __forceinline__ float dot4(float4 a, float4 b) {
    return a.x * b.x + a.y * b.y + a.z * b.z + a.w * b.w;
}

__device__ __forceinline__ unsigned short f32_to_bf16(float f) {
    unsigned bits = __float_as_uint(f);
    unsigned r = (bits + 0x7FFFu + ((bits >> 16) & 1u)) >> 16;
    return (unsigned short)r;
}
__device__ __forceinline__ float bf16_to_f32(unsigned short u) {
    return __uint_as_float((unsigned)u << 16);
}

// ---------------------------------------------------------------------------
// Bjorck device passes (8-block row split; blk = 0..7, 8 rows each).
// ---------------------------------------------------------------------------
__device__ __forceinline__ void mmd(const float* A, const float* B, float* C,
                                    float* CB, int t, int blk) {
    int c = t & 63;
    int r0 = blk * 8 + (t >> 6) * 2;
    float acc0 = 0.f, acc1 = 0.f;
#pragma unroll
    for (int k4 = 0; k4 < 16; ++k4) {
        float4 b  = *(const float4*)&B[c * 64 + k4 * 4];
        float4 a0 = *(const float4*)&A[r0 * 64 + k4 * 4];
        float4 a1 = *(const float4*)&A[(r0 + 1) * 64 + k4 * 4];
        acc0 += dot4(a0, b);
        acc1 += dot4(a1, b);
    }
    C[r0 * 64 + c] = acc0;
    C[(r0 + 1) * 64 + c] = acc1;
    if (CB != nullptr) {
        CB[r0 * 64 + c]       = ((r0 == c)     ? 1.5f : 0.0f) - 0.5f * acc0;
        CB[(r0 + 1) * 64 + c] = ((r0 + 1 == c) ? 1.5f : 0.0f) - 0.5f * acc1;
    }
}

__device__ __forceinline__ void gramd(const float* W, float* G, int t, int blk) {
    int c = t & 63;
    int r0 = blk * 8 + (t >> 6) * 2;
    float acc0 = 0.f, acc1 = 0.f;
#pragma unroll
    for (int k4 = 0; k4 < 32; ++k4) {
        float4 b  = *(const float4*)&W[c * 128 + k4 * 4];
        float4 a0 = *(const float4*)&W[r0 * 128 + k4 * 4];
        float4 a1 = *(const float4*)&W[(r0 + 1) * 128 + k4 * 4];
        acc0 += dot4(a0, b);
        acc1 += dot4(a1, b);
    }
    G[r0 * 64 + c] = acc0;
    G[(r0 + 1) * 64 + c] = acc1;
}

__device__ __forceinline__ void powerd(const float* gH2, float* gSc, int t) {
    float tr = gH2[t * 65];
#pragma unroll
    for (int d = 1; d < 64; d <<= 1) tr += __shfl_xor(tr, d);
    float inv_tr = 1.0f / tr;
    float4 g4[16];
#pragma unroll
    for (int j4 = 0; j4 < 16; ++j4) {
        float4 v = *(const float4*)&gH2[t * 64 + j4 * 4];
        v.x *= inv_tr; v.y *= inv_tr; v.z *= inv_tr; v.w *= inv_tr;
        g4[j4] = v;
    }
    unsigned h = (unsigned)t * 2654435761u;
    float xv = 0.5f + (float)((h >> 17) & 0x7fff) * (1.0f / 32768.0f);
    float yv = 0.f;
    for (int it = 0; it < 8; ++it) {
        float p0 = 0.f, p1 = 0.f, p2 = 0.f, p3 = 0.f;
#pragma unroll
        for (int j4 = 0; j4 < 16; ++j4) {
            float4 xx;
            xx.x = __shfl(xv, j4 * 4 + 0);
            xx.y = __shfl(xv, j4 * 4 + 1);
            xx.z = __shfl(xv, j4 * 4 + 2);
            xx.w = __shfl(xv, j4 * 4 + 3);
            float dd = dot4(g4[j4], xx);
            if (j4 < 4) p0 += dd; else if (j4 < 8) p1 += dd;
            else if (j4 < 12) p2 += dd; else p3 += dd;
        }
        yv = (p0 + p1) + (p2 + p3);
        if (it < 7) xv = yv;
    }
    float num = xv * yv, den = xv * xv;
#pragma unroll
    for (int d = 1; d < 64; d <<= 1) {
        num += __shfl_xor(num, d);
        den += __shfl_xor(den, d);
    }
    if (t == 0) {
        float lam_h2 = tr * num / den;        // = sigma^8
        float sig = powf(lam_h2, 0.125f);
        gSc[0] = 1.0f / (1.1f * sig);
        gSc[1] = 1.0f / (1.21f * sig * sig);
    }
}

__device__ __forceinline__ void wod(const float* W, const float* P,
                                    const float* gSc, float* Wo, int t, int blk) {
    int c = t & 63;
    int r0 = blk * 8 + (t >> 6) * 2;
    float a00 = 0.f, a01 = 0.f, a10 = 0.f, a11 = 0.f;
#pragma unroll 4
    for (int j = 0; j < 64; ++j) {
        float p0 = P[r0 * 64 + j];
        float p1 = P[(r0 + 1) * 64 + j];
        float w0 = W[j * 128 + c];
        float w1 = W[j * 128 + c + 64];
        a00 += p0 * w0; a01 += p0 * w1;
        a10 += p1 * w0; a11 += p1 * w1;
    }
    float sc = gSc[0];
    Wo[r0 * 128 + c]            = sc * a00;
    Wo[r0 * 128 + c + 64]       = sc * a01;
    Wo[(r0 + 1) * 128 + c]      = sc * a10;
    Wo[(r0 + 1) * 128 + c + 64] = sc * a11;
}

// ---------------------------------------------------------------------------
// Cooperative fused Bjorck chain: 16 blocks x 256 (proven in round 15).
// ---------------------------------------------------------------------------
__global__ __launch_bounds__(256) void bjorck_coop(const float* __restrict__ W,
                                                   float* __restrict__ S,
                                                   float* __restrict__ Wo) {
    cg::grid_group g = cg::this_grid();
    int t = threadIdx.x;
    int b16 = blockIdx.x;
    bool second = (b16 >= 8);
    int blk = b16 & 7;
    float* gG  = S;          float* gT  = S + 4096;  float* gA  = S + 8192;
    float* gAn = S + 12288;  float* gA0 = S + 16384; float* gP  = S + 20480;
    float* gPn = S + 24576;  float* gB0 = S + 28672; float* gB1 = S + 32768;
    float* gB2 = S + 36864;  float* gB3 = S + 40960; float* gB4 = S + 45056;
    float* gSc = S + 49152;

    if (!second) gramd(W, gG, t, blk);                          // G
    __threadfence(); g.sync();
    if (!second) mmd(gG, gG, gT, nullptr, t, blk);              // H = G^2
    __threadfence(); g.sync();
    if (!second) mmd(gT, gT, gA, nullptr, t, blk);              // H2 = G^4
    __threadfence(); g.sync();
    if (b16 == 0 && t < 64) powerd(gA, gSc, t);                 // sc, rs
    __threadfence(); g.sync();
    {
        int idx = b16 * 256 + t;
        if (idx < 4096) {
            float rs = gSc[1];
            int r = idx >> 6, c2 = idx & 63;
            float a0 = rs * gG[idx];
            gA0[idx] = a0;
            gB0[idx] = ((r == c2) ? 1.5f : 0.0f) - 0.5f * a0;
        }
    }
    __threadfence(); g.sync();
    if (!second) mmd(gA0, gB0, gT, nullptr, t, blk);            // T = A0@B0
    __threadfence(); g.sync();
    if (!second) mmd(gT, gB0, gA, gB1, t, blk);                 // A1 (+B1)
    __threadfence(); g.sync();
    mmd(second ? gA : gB0, gB1, second ? gT : gP, nullptr, t, blk); // P=B0B1, T=A1B1
    __threadfence(); g.sync();
    if (!second) mmd(gT, gB1, gAn, gB2, t, blk);                // A2 (+B2)
    __threadfence(); g.sync();
    mmd(second ? gAn : gP, gB2, second ? gT : gPn, nullptr, t, blk); // Pn=PB2, T=A2B2
    __threadfence(); g.sync();
    if (!second) mmd(gT, gB2, gA, gB3, t, blk);                 // A3 (+B3)
    __threadfence(); g.sync();
    mmd(second ? gA : gPn, gB3, second ? gT : gP, nullptr, t, blk);  // P=PnB3, T=A3B3
    __threadfence(); g.sync();
    if (!second) mmd(gT, gB3, gAn, gB4, t, blk);                // A4 (+B4)
    __threadfence(); g.sync();
    if (!second) mmd(gP, gB4, gPn, nullptr, t, blk);            // P final
    __threadfence(); g.sync();
    if (!second) wod(W, gPn, gSc, Wo, t, blk);                  // Wo
}

// ---------------------------------------------------------------------------
// per-node prep
// ---------------------------------------------------------------------------
__global__ void node_prep(const float* __restrict__ diags,
                          const float* m1, const float* m2, const float* m3,
                          const float* e1, const float* e2, const float* e3,
                          float* __restrict__ d_e2m, float* __restrict__ d_e3p,
                          float* __restrict__ gso2, int n) {
    int i = blockIdx.x * blockDim.x + threadIdx.x;
    if (i >= n) return;
    float d = diags[i];
    float p1 = safe_pow(d, e1[0]);
    float p2 = safe_pow(d, e2[0]);
    float p3 = safe_pow(d, e3[0]);
    float vm2 = m2[0];
    d_e2m[i] = vm2 * p2;
    d_e3p[i] = p3;
    gso2[i] = m1[0] * p1 + vm2 * p2 * p3 + m3[0];
}

// ---------------------------------------------------------------------------
// xw = x @ Wo^T — register-tiled GEMM; OUTPUT IN BF16.
// ---------------------------------------------------------------------------
#define XN 64
#define XS 132
__global__ __launch_bounds__(256) void xw_kernel(const float* __restrict__ x,
                                                 const float* __restrict__ Wo,
                                                 unsigned short* __restrict__ xwb,
                                                 int n) {
    __shared__ __align__(16) float xs[XN * XS];
    __shared__ __align__(16) float ws[DOUT * XS];
    int t = threadIdx.x;
    int base = blockIdx.x * XN;
    for (int f = t; f < DOUT * (DIN / 4); f += 256) {
        int r = f >> 5, c = f & 31;
        *(float4*)&ws[r * XS + c * 4] = *(const float4*)&Wo[r * DIN + c * 4];
    }
    for (int f = t; f < XN * (DIN / 4); f += 256) {
        int r = f >> 5, c = f & 31;
        int node = base + r;
        float4 v = make_float4(0.f, 0.f, 0.f, 0.f);
        if (node < n) v = *(const float4*)&x[(size_t)node * DIN + c * 4];
        *(float4*)&xs[r * XS + c * 4] = v;
    }
    __syncthreads();
    int tn = t >> 4;
    int td = t & 15;
    float acc[4][4] = {};
#pragma unroll 2
    for (int k4 = 0; k4 < DIN / 4; ++k4) {
        float4 a[4], w[4];
#pragma unroll
        for (int r = 0; r < 4; ++r) a[r] = *(const float4*)&xs[(tn * 4 + r) * XS + k4 * 4];
#pragma unroll
        for (int c = 0; c < 4; ++c) w[c] = *(const float4*)&ws[(td + c * 16) * XS + k4 * 4];
#pragma unroll
        for (int r = 0; r < 4; ++r)
#pragma unroll
            for (int c = 0; c < 4; ++c) acc[r][c] += dot4(a[r], w[c]);
    }
#pragma unroll
    for (int r = 0; r < 4; ++r) {
        int node = base + tn * 4 + r;
        if (node >= n) break;
#pragma unroll
        for (int c = 0; c < 4; ++c)
            xwb[(size_t)node * DOUT + td + c * 16] = f32_to_bf16(acc[r][c]);
    }
}

// ---------------------------------------------------------------------------
// Cooperative fused sort chain, grid = nbk blocks (one per bucket for CSR).
// ROUND-15 LESSON: hist/scatter must use NCHK=64 fat chunks (~25000 edges,
// ~32-edge per-(chunk,bucket) runs -> L2 line merging). Blocks 64..nbk-1
// idle through phases A/D at the grid syncs.
// ---------------------------------------------------------------------------
__global__ __launch_bounds__(256) void sort_coop(const int* __restrict__ ei,
                                                 const float* __restrict__ d_e2m,
                                                 unsigned* __restrict__ blk_hist,
                                                 unsigned* __restrict__ btot,
                                                 unsigned* __restrict__ boff,
                                                 unsigned* __restrict__ bucketed,
                                                 int* __restrict__ offsets,
                                                 uint2* __restrict__ pairs,
                                                 int n, int e_cnt, int nbk, int chunk) {
    cg::grid_group g = cg::this_grid();
    __shared__ int h[NBK_STRIDE];
    __shared__ unsigned sE[CCAP];
    __shared__ int sh2[256];
    __shared__ int shc[BK_COLS], scc[BK_COLS], posc[BK_COLS];
    int b = blockIdx.x, t = threadIdx.x;
    int lo = b * chunk, hi = min(lo + chunk, e_cnt);

    // Phase A: per-chunk bucket histogram (blocks 0..NCHK-1 only)
    if (b < NCHK) {
        for (int j = t; j < NBK_STRIDE; j += 256) h[j] = 0;
        __syncthreads();
        for (int e = lo + t; e < hi; e += 256)
            atomicAdd(&h[ei[e_cnt + e] >> BK_SHIFT], 1);
        __syncthreads();
        for (int j = t; j < nbk; j += 256)
            blk_hist[(size_t)b * NBK_STRIDE + j] = (unsigned)h[j];
    }
    __threadfence(); g.sync();

    // Phase B: wave 0 of block b scans bucket b's 64-entry column
    if (t < 64) {
        unsigned v = blk_hist[(size_t)t * NBK_STRIDE + b];
        unsigned incl = v;
#pragma unroll
        for (int d = 1; d < 64; d <<= 1) {
            unsigned u = __shfl_up(incl, d);
            if ((int)(t) >= d) incl += u;
        }
        blk_hist[(size_t)t * NBK_STRIDE + b] = incl - v;   // exclusive prefix
        if (t == 63) btot[b] = incl;
    }
    __threadfence(); g.sync();

    // Phase C: block 0 scans bucket totals -> boff
    if (b == 0) {
        int base = t * 4;
        int v[4];
        int s = 0;
#pragma unroll
        for (int k = 0; k < 4; ++k) {
            int j = base + k;
            v[k] = (j < nbk) ? (int)btot[j] : 0;
            s += v[k];
        }
        sh2[t] = s;
        __syncthreads();
        for (int d = 1; d < 256; d <<= 1) {
            int u = (t >= d) ? sh2[t - d] : 0;
            __syncthreads();
            sh2[t] += u;
            __syncthreads();
        }
        int run = sh2[t] - s;
#pragma unroll
        for (int k = 0; k < 4; ++k) {
            int j = base + k;
            if (j < nbk) boff[j] = (unsigned)run;
            run += v[k];
        }
        if (t == 0) boff[nbk] = (unsigned)e_cnt;
    }
    __threadfence(); g.sync();

    // Phase D: scatter packed keys into reserved runs (blocks 0..NCHK-1)
    if (b < NCHK) {
        for (int j = t; j < nbk; j += 256)
            h[j] = (int)(boff[j] + blk_hist[(size_t)b * NBK_STRIDE + j]);
        __syncthreads();
        for (int e = lo + t; e < hi; e += 256) {
            int col = ei[e_cnt + e];
            int src = ei[e];
            int pos = atomicAdd(&h[col >> BK_SHIFT], 1);
            bucketed[pos] = ((unsigned)src << BK_SHIFT) | (unsigned)(col & (BK_COLS - 1));
        }
    }
    __threadfence(); g.sync();

    // Phase E: per-bucket exact CSR + (src, weight) pairs (all nbk blocks)
    {
        int base2 = (int)boff[b];
        int cnt = (int)boff[b + 1] - base2;
        bool fits = (cnt <= CCAP);
        if (fits)
            for (int i = t; i < cnt; i += 256) sE[i] = bucketed[base2 + i];
        if (t < BK_COLS) shc[t] = 0;
        __syncthreads();
        for (int i = t; i < cnt; i += 256) {
            unsigned p = fits ? sE[i] : bucketed[base2 + i];
            atomicAdd(&shc[p & (BK_COLS - 1)], 1);
        }
        __syncthreads();
        if (t < BK_COLS) scc[t] = shc[t];
        __syncthreads();
        for (int d = 1; d < BK_COLS; d <<= 1) {
            int u = 0;
            if (t < BK_COLS && t >= d) u = scc[t - d];
            __syncthreads();
            if (t < BK_COLS) scc[t] += u;
            __syncthreads();
        }
        if (t < BK_COLS) {
            int pre = scc[t] - shc[t];
            int gc = b * BK_COLS + t;
            if (gc < n) offsets[gc] = base2 + pre;
            posc[t] = pre;
        }
        if (b == 0 && t == 0) offsets[n] = e_cnt;
        __syncthreads();
        for (int i = t; i < cnt; i += 256) {
            unsigned p = fits ? sE[i] : bucketed[base2 + i];
            int lc = (int)(p & (BK_COLS - 1));
            unsigned s = p >> BK_SHIFT;
            int q = atomicAdd(&posc[lc], 1);
            uint2 o;
            o.x = s;
            o.y = __float_as_uint(d_e2m[s]);
            pairs[base2 + q] = o;
        }
    }
}

// ---------------------------------------------------------------------------
// fused gather + self-loop + bias + log-softmax; one wave per node.
// (round-12 version — best measured)
// ---------------------------------------------------------------------------
__global__ __launch_bounds__(256) void gather_kernel(const int* __restrict__ offsets,
                                                     const uint2* __restrict__ pairs,
                                                     const float* __restrict__ d_e3p,
                                                     const unsigned short* __restrict__ xwb,
                                                     const float* __restrict__ gso2,
                                                     const float* __restrict__ b,
                                                     float* __restrict__ out, int n) {
    unsigned lane = threadIdx.x & 63;
    int node = blockIdx.x * 4 + (threadIdx.x >> 6);
    if (node >= n) return;
    int lo = offsets[node], hi = offsets[node + 1];
    float xself = bf16_to_f32(xwb[(size_t)node * DOUT + lane]);
    float v = gso2[node] * xself + 2.0f * b[lane];
    float dn = d_e3p[node];
    float accA = 0.f, accB = 0.f;
    int i = lo;
    for (; i + 8 <= hi; i += 8) {
        uint2 p0 = pairs[i + 0], p1 = pairs[i + 1], p2 = pairs[i + 2], p3 = pairs[i + 3];
        uint2 p4 = pairs[i + 4], p5 = pairs[i + 5], p6 = pairs[i + 6], p7 = pairs[i + 7];
        float a0 = bf16_to_f32(xwb[p0.x * 64u + lane]);
        float a1 = bf16_to_f32(xwb[p1.x * 64u + lane]);
        float a2 = bf16_to_f32(xwb[p2.x * 64u + lane]);
        float a3 = bf16_to_f32(xwb[p3.x * 64u + lane]);
        float a4 = bf16_to_f32(xwb[p4.x * 64u + lane]);
        float a5 = bf16_to_f32(xwb[p5.x * 64u + lane]);
        float a6 = bf16_to_f32(xwb[p6.x * 64u + lane]);
        float a7 = bf16_to_f32(xwb[p7.x * 64u + lane]);
        accA += __uint_as_float(p0.y) * a0 + __uint_as_float(p1.y) * a1
              + __uint_as_float(p2.y) * a2 + __uint_as_float(p3.y) * a3;
        accB += __uint_as_float(p4.y) * a4 + __uint_as_float(p5.y) * a5
              + __uint_as_float(p6.y) * a6 + __uint_as_float(p7.y) * a7;
    }
    for (; i + 2 <= hi; i += 2) {
        uint2 p0 = pairs[i + 0], p1 = pairs[i + 1];
        float a0 = bf16_to_f32(xwb[p0.x * 64u + lane]);
        float a1 = bf16_to_f32(xwb[p1.x * 64u + lane]);
        accA += __uint_as_float(p0.y) * a0;
        accB += __uint_as_float(p1.y) * a1;
    }
    if (i < hi) {
        uint2 p = pairs[i];
        accA += __uint_as_float(p.y) * bf16_to_f32(xwb[p.x * 64u + lane]);
    }
    v += dn * (accA + accB);
    float m = v;
#pragma unroll
    for (int d = 1; d < 64; d <<= 1) m = fmaxf(m, __shfl_xor(m, d));
    float s = expf(v - m);
#pragma unroll
    for (int d = 1; d < 64; d <<= 1) s += __shfl_xor(s, d);
    out[(size_t)node * DOUT + lane] = v - m - logf(s);
}

// ---------------------------------------------------------------------------
extern "C" void kernel_launch(void* const* d_in, const int* in_sizes, int n_in,
                              void* d_out, int out_size, void* d_ws, size_t ws_size,
                              hipStream_t stream) {
    const float* x     = (const float*)d_in[0];
    const int*   ei    = (const int*)d_in[1];
    const float* diags = (const float*)d_in[3];
    const float* W     = (const float*)d_in[4];
    const float* b     = (const float*)d_in[5];
    const float* m1    = (const float*)d_in[6];
    const float* m2    = (const float*)d_in[7];
    const float* m3    = (const float*)d_in[8];
    const float* e1    = (const float*)d_in[9];
    const float* e2    = (const float*)d_in[10];
    const float* e3    = (const float*)d_in[11];
    float* out = (float*)d_out;

    const int n = in_sizes[3];            // 100000
    const int e_cnt = in_sizes[1] / 2;    // 1600000
    const int nbk = (n + BK_COLS - 1) >> BK_SHIFT;          // 782 buckets
    const int chunk = (e_cnt + NCHK - 1) / NCHK;            // 25000 edges/chunk

    char* ws = (char*)d_ws;
    // --- small-matrix region (fixed offsets) ---
    float*    Wo   = (float*)ws;                 // 8192 floats = 32KB
    float*    S    = (float*)(ws + 32768);       // bjorck scratch: 13x4096 f
    // --- big arrays ---
    float*          d_e2m    = S + 53248;              // n
    float*          d_e3p    = d_e2m + n;              // n
    float*          gso2     = d_e3p + n;              // n
    unsigned short* xwb      = (unsigned short*)(gso2 + n);   // n*64 bf16
    int*            offsets  = (int*)(xwb + (size_t)n * DOUT); // n+4
    unsigned*       bucketed = (unsigned*)(offsets + n + 4);   // e_cnt
    unsigned*       blk_hist = bucketed + e_cnt;               // NCHK*1024
    unsigned*       btot     = blk_hist + (size_t)NCHK * NBK_STRIDE; // nbk pad 1024
    unsigned*       boff     = btot + 1024;                    // nbk+8
    uintptr_t pp = ((uintptr_t)(boff + nbk + 8) + 15) & ~(uintptr_t)15;
    uint2*          pairs    = (uint2*)pp;                     // e_cnt (8B)

    // ---- Bjorck chain: ONE cooperative kernel ------------------------------
    {
        void* args[] = { (void*)&W, (void*)&S, (void*)&Wo };
        hipLaunchCooperativeKernel((const void*)bjorck_coop, dim3(16), dim3(256),
                                   args, 0, stream);
    }
    // ---- node prep + feature transform ------------------------------------
    node_prep<<<(n + 255) / 256, 256, 0, stream>>>(diags, m1, m2, m3, e1, e2, e3,
                                                   d_e2m, d_e3p, gso2, n);
    xw_kernel<<<(n + XN - 1) / XN, 256, 0, stream>>>(x, Wo, xwb, n);
    // ---- sort chain: ONE cooperative kernel (64-chunk hist/scatter) --------
    {
        int n_ = n, e_ = e_cnt, nbk_ = nbk, ch_ = chunk;
        void* args[] = { (void*)&ei, (void*)&d_e2m, (void*)&blk_hist, (void*)&btot,
                         (void*)&boff, (void*)&bucketed, (void*)&offsets,
                         (void*)&pairs, (void*)&n_, (void*)&e_, (void*)&nbk_,
                         (void*)&ch_ };
        hipLaunchCooperativeKernel((const void*)sort_coop, dim3(nbk), dim3(256),
                                   args, 0, stream);
    }
    // ---- fused gather + softmax --------------------------------------------
    gather_kernel<<<(n + 3) / 4, 256, 0, stream>>>(offsets, pairs, d_e3p,
                                                   xwb, gso2, b, out, n);
}

// Round 17
// 320.896 us; speedup vs baseline: 2.7635x; 2.7222x over previous
//
#include <hip/hip_runtime.h>
#include <hip/hip_cooperative_groups.h>
#include <math.h>

namespace cg = cooperative_groups;

#define DIN 128
#define DOUT 64

#define NBLK 64             // binning blocks for hist/scatter (write locality)
#define BK_SHIFT 7          // 128 cols per bucket
#define BK_COLS 128
#define NBK_STRIDE 1024     // blk_hist row stride
#define CCAP 4096           // max edges per bucket staged in LDS (mean ~2046)

__device__ __forceinline__ float safe_pow(float d, float e) {
    float p = powf(d, e);
    return isinf(p) ? 0.0f : p;
}

__device__ __forceinline__ float dot4(float4 a, float4 b) {
    return a.x * b.x + a.y * b.y + a.z * b.z + a.w * b.w;
}

__device__ __forceinline__ unsigned short f32_to_bf16(float f) {
    unsigned bits = __float_as_uint(f);
    unsigned r = (bits + 0x7FFFu + ((bits >> 16) & 1u)) >> 16;
    return (unsigned short)r;
}

// ---------------------------------------------------------------------------
// Bjorck device passes (8-block row split; blk = 0..7, 8 rows each).
// ---------------------------------------------------------------------------
__device__ __forceinline__ void mmd(const float* A, const float* B, float* C,
                                    float* CB, int t, int blk) {
    int c = t & 63;
    int r0 = blk * 8 + (t >> 6) * 2;
    float acc0 = 0.f, acc1 = 0.f;
#pragma unroll
    for (int k4 = 0; k4 < 16; ++k4) {
        float4 b  = *(const float4*)&B[c * 64 + k4 * 4];
        float4 a0 = *(const float4*)&A[r0 * 64 + k4 * 4];
        float4 a1 = *(const float4*)&A[(r0 + 1) * 64 + k4 * 4];
        acc0 += dot4(a0, b);
        acc1 += dot4(a1, b);
    }
    C[r0 * 64 + c] = acc0;
    C[(r0 + 1) * 64 + c] = acc1;
    if (CB != nullptr) {
        CB[r0 * 64 + c]       = ((r0 == c)     ? 1.5f : 0.0f) - 0.5f * acc0;
        CB[(r0 + 1) * 64 + c] = ((r0 + 1 == c) ? 1.5f : 0.0f) - 0.5f * acc1;
    }
}

__device__ __forceinline__ void gramd(const float* W, float* G, int t, int blk) {
    int c = t & 63;
    int r0 = blk * 8 + (t >> 6) * 2;
    float acc0 = 0.f, acc1 = 0.f;
#pragma unroll
    for (int k4 = 0; k4 < 32; ++k4) {
        float4 b  = *(const float4*)&W[c * 128 + k4 * 4];
        float4 a0 = *(const float4*)&W[r0 * 128 + k4 * 4];
        float4 a1 = *(const float4*)&W[(r0 + 1) * 128 + k4 * 4];
        acc0 += dot4(a0, b);
        acc1 += dot4(a1, b);
    }
    G[r0 * 64 + c] = acc0;
    G[(r0 + 1) * 64 + c] = acc1;
}

__device__ __forceinline__ void powerd(const float* gH2, float* gSc, int t) {
    float tr = gH2[t * 65];
#pragma unroll
    for (int d = 1; d < 64; d <<= 1) tr += __shfl_xor(tr, d);
    float inv_tr = 1.0f / tr;
    float4 g4[16];
#pragma unroll
    for (int j4 = 0; j4 < 16; ++j4) {
        float4 v = *(const float4*)&gH2[t * 64 + j4 * 4];
        v.x *= inv_tr; v.y *= inv_tr; v.z *= inv_tr; v.w *= inv_tr;
        g4[j4] = v;
    }
    unsigned h = (unsigned)t * 2654435761u;
    float xv = 0.5f + (float)((h >> 17) & 0x7fff) * (1.0f / 32768.0f);
    float yv = 0.f;
    for (int it = 0; it < 8; ++it) {
        float p0 = 0.f, p1 = 0.f, p2 = 0.f, p3 = 0.f;
#pragma unroll
        for (int j4 = 0; j4 < 16; ++j4) {
            float4 xx;
            xx.x = __shfl(xv, j4 * 4 + 0);
            xx.y = __shfl(xv, j4 * 4 + 1);
            xx.z = __shfl(xv, j4 * 4 + 2);
            xx.w = __shfl(xv, j4 * 4 + 3);
            float dd = dot4(g4[j4], xx);
            if (j4 < 4) p0 += dd; else if (j4 < 8) p1 += dd;
            else if (j4 < 12) p2 += dd; else p3 += dd;
        }
        yv = (p0 + p1) + (p2 + p3);
        if (it < 7) xv = yv;
    }
    float num = xv * yv, den = xv * xv;
#pragma unroll
    for (int d = 1; d < 64; d <<= 1) {
        num += __shfl_xor(num, d);
        den += __shfl_xor(den, d);
    }
    if (t == 0) {
        float lam_h2 = tr * num / den;        // = sigma^8
        float sig = powf(lam_h2, 0.125f);
        gSc[0] = 1.0f / (1.1f * sig);
        gSc[1] = 1.0f / (1.21f * sig * sig);
    }
}

__device__ __forceinline__ void wod(const float* W, const float* P,
                                    const float* gSc, float* Wo, int t, int blk) {
    int c = t & 63;
    int r0 = blk * 8 + (t >> 6) * 2;
    float a00 = 0.f, a01 = 0.f, a10 = 0.f, a11 = 0.f;
#pragma unroll 4
    for (int j = 0; j < 64; ++j) {
        float p0 = P[r0 * 64 + j];
        float p1 = P[(r0 + 1) * 64 + j];
        float w0 = W[j * 128 + c];
        float w1 = W[j * 128 + c + 64];
        a00 += p0 * w0; a01 += p0 * w1;
        a10 += p1 * w0; a11 += p1 * w1;
    }
    float sc = gSc[0];
    Wo[r0 * 128 + c]            = sc * a00;
    Wo[r0 * 128 + c + 64]       = sc * a01;
    Wo[(r0 + 1) * 128 + c]      = sc * a10;
    Wo[(r0 + 1) * 128 + c + 64] = sc * a11;
}

// ---------------------------------------------------------------------------
// Cooperative fused Bjorck chain: 16 blocks x 256.
// NARROW grid only — grid.sync() at ~800 blocks costs ~130 µs/sync (round-16
// lesson); at 16 blocks it is cheap and this kernel is proven correct.
// ---------------------------------------------------------------------------
__global__ __launch_bounds__(256) void bjorck_coop(const float* __restrict__ W,
                                                   float* __restrict__ S,
                                                   float* __restrict__ Wo) {
    cg::grid_group g = cg::this_grid();
    int t = threadIdx.x;
    int b16 = blockIdx.x;
    bool second = (b16 >= 8);
    int blk = b16 & 7;
    float* gG  = S;          float* gT  = S + 4096;  float* gA  = S + 8192;
    float* gAn = S + 12288;  float* gA0 = S + 16384; float* gP  = S + 20480;
    float* gPn = S + 24576;  float* gB0 = S + 28672; float* gB1 = S + 32768;
    float* gB2 = S + 36864;  float* gB3 = S + 40960; float* gB4 = S + 45056;
    float* gSc = S + 49152;

    if (!second) gramd(W, gG, t, blk);                          // G
    __threadfence(); g.sync();
    if (!second) mmd(gG, gG, gT, nullptr, t, blk);              // H = G^2
    __threadfence(); g.sync();
    if (!second) mmd(gT, gT, gA, nullptr, t, blk);              // H2 = G^4
    __threadfence(); g.sync();
    if (b16 == 0 && t < 64) powerd(gA, gSc, t);                 // sc, rs
    __threadfence(); g.sync();
    {
        int idx = b16 * 256 + t;
        if (idx < 4096) {
            float rs = gSc[1];
            int r = idx >> 6, c2 = idx & 63;
            float a0 = rs * gG[idx];
            gA0[idx] = a0;
            gB0[idx] = ((r == c2) ? 1.5f : 0.0f) - 0.5f * a0;
        }
    }
    __threadfence(); g.sync();
    if (!second) mmd(gA0, gB0, gT, nullptr, t, blk);            // T = A0@B0
    __threadfence(); g.sync();
    if (!second) mmd(gT, gB0, gA, gB1, t, blk);                 // A1 (+B1)
    __threadfence(); g.sync();
    mmd(second ? gA : gB0, gB1, second ? gT : gP, nullptr, t, blk); // P=B0B1, T=A1B1
    __threadfence(); g.sync();
    if (!second) mmd(gT, gB1, gAn, gB2, t, blk);                // A2 (+B2)
    __threadfence(); g.sync();
    mmd(second ? gAn : gP, gB2, second ? gT : gPn, nullptr, t, blk); // Pn=PB2, T=A2B2
    __threadfence(); g.sync();
    if (!second) mmd(gT, gB2, gA, gB3, t, blk);                 // A3 (+B3)
    __threadfence(); g.sync();
    mmd(second ? gA : gPn, gB3, second ? gT : gP, nullptr, t, blk);  // P=PnB3, T=A3B3
    __threadfence(); g.sync();
    if (!second) mmd(gT, gB3, gAn, gB4, t, blk);                // A4 (+B4)
    __threadfence(); g.sync();
    if (!second) mmd(gP, gB4, gPn, nullptr, t, blk);            // P final
    __threadfence(); g.sync();
    if (!second) wod(W, gPn, gSc, Wo, t, blk);                  // Wo
}

// ---------------------------------------------------------------------------
// per-node prep
// ---------------------------------------------------------------------------
__global__ void node_prep(const float* __restrict__ diags,
                          const float* m1, const float* m2, const float* m3,
                          const float* e1, const float* e2, const float* e3,
                          float* __restrict__ d_e2m, float* __restrict__ d_e3p,
                          float* __restrict__ gso2, int n) {
    int i = blockIdx.x * blockDim.x + threadIdx.x;
    if (i >= n) return;
    float d = diags[i];
    float p1 = safe_pow(d, e1[0]);
    float p2 = safe_pow(d, e2[0]);
    float p3 = safe_pow(d, e3[0]);
    float vm2 = m2[0];
    d_e2m[i] = vm2 * p2;
    d_e3p[i] = p3;
    gso2[i] = m1[0] * p1 + vm2 * p2 * p3 + m3[0];
}

// ---------------------------------------------------------------------------
// xw = x @ Wo^T — register-tiled GEMM; OUTPUT IN BF16.
// ---------------------------------------------------------------------------
#define XN 64
#define XS 132
__global__ __launch_bounds__(256) void xw_kernel(const float* __restrict__ x,
                                                 const float* __restrict__ Wo,
                                                 unsigned short* __restrict__ xwb,
                                                 int n) {
    __shared__ __align__(16) float xs[XN * XS];
    __shared__ __align__(16) float ws[DOUT * XS];
    int t = threadIdx.x;
    int base = blockIdx.x * XN;
    for (int f = t; f < DOUT * (DIN / 4); f += 256) {
        int r = f >> 5, c = f & 31;
        *(float4*)&ws[r * XS + c * 4] = *(const float4*)&Wo[r * DIN + c * 4];
    }
    for (int f = t; f < XN * (DIN / 4); f += 256) {
        int r = f >> 5, c = f & 31;
        int node = base + r;
        float4 v = make_float4(0.f, 0.f, 0.f, 0.f);
        if (node < n) v = *(const float4*)&x[(size_t)node * DIN + c * 4];
        *(float4*)&xs[r * XS + c * 4] = v;
    }
    __syncthreads();
    int tn = t >> 4;
    int td = t & 15;
    float acc[4][4] = {};
#pragma unroll 2
    for (int k4 = 0; k4 < DIN / 4; ++k4) {
        float4 a[4], w[4];
#pragma unroll
        for (int r = 0; r < 4; ++r) a[r] = *(const float4*)&xs[(tn * 4 + r) * XS + k4 * 4];
#pragma unroll
        for (int c = 0; c < 4; ++c) w[c] = *(const float4*)&ws[(td + c * 16) * XS + k4 * 4];
#pragma unroll
        for (int r = 0; r < 4; ++r)
#pragma unroll
            for (int c = 0; c < 4; ++c) acc[r][c] += dot4(a[r], w[c]);
    }
#pragma unroll
    for (int r = 0; r < 4; ++r) {
        int node = base + tn * 4 + r;
        if (node >= n) break;
#pragma unroll
        for (int c = 0; c < 4; ++c)
            xwb[(size_t)node * DOUT + td + c * 16] = f32_to_bf16(acc[r][c]);
    }
}

// ---------------------------------------------------------------------------
// Sort pass B1: per-block bucket histograms (bucket = col >> 7).
// ---------------------------------------------------------------------------
__global__ __launch_bounds__(256) void b1_hist(const int* __restrict__ ei,
                                               unsigned* __restrict__ blk_hist,
                                               int e_cnt, int chunk, int nbk) {
    __shared__ int h[NBK_STRIDE];
    int b = blockIdx.x, t = threadIdx.x;
    for (int j = t; j < NBK_STRIDE; j += 256) h[j] = 0;
    __syncthreads();
    int lo = b * chunk, hi = min(lo + chunk, e_cnt);
    for (int e = lo + t; e < hi; e += 256)
        atomicAdd(&h[ei[e_cnt + e] >> BK_SHIFT], 1);
    __syncthreads();
    for (int j = t; j < nbk; j += 256)
        blk_hist[(size_t)b * NBK_STRIDE + j] = (unsigned)h[j];
}

// ---------------------------------------------------------------------------
// Sort pass S: scan bucket totals -> bucket_offsets + per-(block,bucket) bases.
// ---------------------------------------------------------------------------
__global__ __launch_bounds__(1024) void s_scan(unsigned* __restrict__ blk_hist,
                                               unsigned* __restrict__ bucket_offsets,
                                               int nbk, int e_cnt) {
    __shared__ int tot[1024];
    int t = threadIdx.x;
    int total = 0;
    if (t < nbk) {
        int run = 0;
        for (int b = 0; b < NBLK; ++b) {
            size_t idx = (size_t)b * NBK_STRIDE + t;
            int v = (int)blk_hist[idx];
            blk_hist[idx] = (unsigned)run;
            run += v;
        }
        total = run;
    }
    tot[t] = total;
    __syncthreads();
    for (int d = 1; d < 1024; d <<= 1) {
        int u = (t >= d) ? tot[t - d] : 0;
        __syncthreads();
        tot[t] += u;
        __syncthreads();
    }
    int excl = tot[t] - total;
    if (t < nbk) {
        bucket_offsets[t] = (unsigned)excl;
        for (int b = 0; b < NBLK; ++b)
            blk_hist[(size_t)b * NBK_STRIDE + t] += (unsigned)excl;
    }
    if (t == 0) bucket_offsets[nbk] = (unsigned)e_cnt;
}

// ---------------------------------------------------------------------------
// Sort pass B2: scatter packed (src<<7 | lcol) into reserved per-block runs.
// ---------------------------------------------------------------------------
__global__ __launch_bounds__(256) void b2_scatter(const int* __restrict__ ei,
                                                  const unsigned* __restrict__ blk_hist,
                                                  unsigned* __restrict__ bucketed,
                                                  int e_cnt, int chunk, int nbk) {
    __shared__ int cur[NBK_STRIDE];
    int b = blockIdx.x, t = threadIdx.x;
    for (int j = t; j < nbk; j += 256)
        cur[j] = (int)blk_hist[(size_t)b * NBK_STRIDE + j];
    __syncthreads();
    int lo = b * chunk, hi = min(lo + chunk, e_cnt);
    for (int e = lo + t; e < hi; e += 256) {
        int col = ei[e_cnt + e];
        int src = ei[e];
        int bkt = col >> BK_SHIFT;
        int pos = atomicAdd(&cur[bkt], 1);
        bucketed[pos] = ((unsigned)src << BK_SHIFT) | (unsigned)(col & (BK_COLS - 1));
    }
}

// ---------------------------------------------------------------------------
// Sort pass C: one block per bucket -> exact CSR + (src, weight_f32) pairs.
// ---------------------------------------------------------------------------
__global__ __launch_bounds__(256) void c_csr(const unsigned* __restrict__ bucketed,
                                             const unsigned* __restrict__ bucket_offsets,
                                             const float* __restrict__ d_e2m,
                                             int* __restrict__ offsets,
                                             uint2* __restrict__ pairs,
                                             int n, int e_cnt) {
    __shared__ unsigned sE[CCAP];
    __shared__ int sh[BK_COLS];
    __shared__ int sc[BK_COLS];
    __shared__ int pos_[BK_COLS];
    int b = blockIdx.x, t = threadIdx.x;
    int base = (int)bucket_offsets[b];
    int cnt = (int)bucket_offsets[b + 1] - base;
    bool fits = (cnt <= CCAP);
    if (fits)
        for (int i = t; i < cnt; i += 256) sE[i] = bucketed[base + i];
    if (t < BK_COLS) sh[t] = 0;
    __syncthreads();
    for (int i = t; i < cnt; i += 256) {
        unsigned p = fits ? sE[i] : bucketed[base + i];
        atomicAdd(&sh[p & (BK_COLS - 1)], 1);
    }
    __syncthreads();
    if (t < BK_COLS) sc[t] = sh[t];
    __syncthreads();
    for (int d = 1; d < BK_COLS; d <<= 1) {
        int u = 0;
        if (t < BK_COLS && t >= d) u = sc[t - d];
        __syncthreads();
        if (t < BK_COLS) sc[t] += u;
        __syncthreads();
    }
    if (t < BK_COLS) {
        int pre = sc[t] - sh[t];
        int gc = b * BK_COLS + t;
        if (gc < n) offsets[gc] = base + pre;
        pos_[t] = pre;
    }
    if (b == 0 && t == 0) offsets[n] = e_cnt;
    __syncthreads();
    for (int i = t; i < cnt; i += 256) {
        unsigned p = fits ? sE[i] : bucketed[base + i];
        int lc = (int)(p & (BK_COLS - 1));
        unsigned s = p >> BK_SHIFT;
        int q = atomicAdd(&pos_[lc], 1);
        uint2 o;
        o.x = s;
        o.y = __float_as_uint(d_e2m[s]);
        pairs[base + q] = o;
    }
}

// ---------------------------------------------------------------------------
// fused gather + self-loop + bias + log-softmax; one wave per node.
// DWORD-PACKED: each lane loads one uint (2 bf16 dims); lanes 0-31 cover the
// row, the two wave-halves process two edges per load instruction. Targets
// round-12's ~49% VALUBusy: ~half the VALU + load instructions per edge.
// High bf16 of the dword is already float bits (AND); low needs SHL 16.
// ---------------------------------------------------------------------------
__global__ __launch_bounds__(256) void gather_kernel(const int* __restrict__ offsets,
                                                     const uint2* __restrict__ pairs,
                                                     const float* __restrict__ d_e3p,
                                                     const unsigned short* __restrict__ xwb,
                                                     const float* __restrict__ gso2,
                                                     const float* __restrict__ b,
                                                     float* __restrict__ out, int n) {
    unsigned lane = threadIdx.x & 63;
    unsigned half = lane >> 5;          // 0 or 1
    unsigned hl = lane & 31;            // dword index within the 64-dim row
    int node = blockIdx.x * 4 + (threadIdx.x >> 6);
    if (node >= n) return;
    int lo = offsets[node], hi = offsets[node + 1];
    const unsigned* xw32 = (const unsigned*)xwb;   // row stride 32 dwords
    float accLo = 0.f, accHi = 0.f;
    int i = lo;
    // 8 edges/iter: half h handles edges i+4h .. i+4h+3 (4 loads in flight/lane)
    for (; i + 8 <= hi; i += 8) {
        int e0 = i + 4 * half;
        uint2 p0 = pairs[e0 + 0], p1 = pairs[e0 + 1];
        uint2 p2 = pairs[e0 + 2], p3 = pairs[e0 + 3];
        unsigned u0 = xw32[p0.x * 32u + hl];
        unsigned u1 = xw32[p1.x * 32u + hl];
        unsigned u2 = xw32[p2.x * 32u + hl];
        unsigned u3 = xw32[p3.x * 32u + hl];
        float w0 = __uint_as_float(p0.y), w1 = __uint_as_float(p1.y);
        float w2 = __uint_as_float(p2.y), w3 = __uint_as_float(p3.y);
        accLo += w0 * __uint_as_float(u0 << 16) + w1 * __uint_as_float(u1 << 16)
               + w2 * __uint_as_float(u2 << 16) + w3 * __uint_as_float(u3 << 16);
        accHi += w0 * __uint_as_float(u0 & 0xFFFF0000u) + w1 * __uint_as_float(u1 & 0xFFFF0000u)
               + w2 * __uint_as_float(u2 & 0xFFFF0000u) + w3 * __uint_as_float(u3 & 0xFFFF0000u);
    }
    // 4 edges/iter: half h handles edges i+2h, i+2h+1
    for (; i + 4 <= hi; i += 4) {
        int e0 = i + 2 * half;
        uint2 p0 = pairs[e0 + 0], p1 = pairs[e0 + 1];
        unsigned u0 = xw32[p0.x * 32u + hl];
        unsigned u1 = xw32[p1.x * 32u + hl];
        float w0 = __uint_as_float(p0.y), w1 = __uint_as_float(p1.y);
        accLo += w0 * __uint_as_float(u0 << 16) + w1 * __uint_as_float(u1 << 16);
        accHi += w0 * __uint_as_float(u0 & 0xFFFF0000u) + w1 * __uint_as_float(u1 & 0xFFFF0000u);
    }
    // tail (0-3 edges): half 0 takes up to 2, half 1 the third
    {
        int rem = hi - i;
        int j0 = 2 * (int)half;
        int j1 = min(j0 + 2, rem);
        for (int j = j0; j < j1; ++j) {
            uint2 p = pairs[i + j];
            unsigned u = xw32[p.x * 32u + hl];
            float w = __uint_as_float(p.y);
            accLo += w * __uint_as_float(u << 16);
            accHi += w * __uint_as_float(u & 0xFFFF0000u);
        }
    }
    // merge the two halves' edge sums
    accLo += __shfl_xor(accLo, 32);
    accHi += __shfl_xor(accHi, 32);

    // self-loop + bias
    unsigned us = xw32[(unsigned)node * 32u + hl];
    float xsLo = __uint_as_float(us << 16);
    float xsHi = __uint_as_float(us & 0xFFFF0000u);
    float2 bb = *(const float2*)&b[2 * hl];
    float gs = gso2[node], dn = d_e3p[node];
    float vLo = gs * xsLo + 2.0f * bb.x + dn * accLo;
    float vHi = gs * xsHi + 2.0f * bb.y + dn * accHi;
    // log-softmax over 64 dims (2 per lane, 32 lanes; halves hold duplicates)
    float m = fmaxf(vLo, vHi);
#pragma unroll
    for (int d = 1; d < 32; d <<= 1) m = fmaxf(m, __shfl_xor(m, d));
    float s = expf(vLo - m) + expf(vHi - m);
#pragma unroll
    for (int d = 1; d < 32; d <<= 1) s += __shfl_xor(s, d);
    if (half == 0) {
        float ls = logf(s);
        float2 o;
        o.x = vLo - m - ls;
        o.y = vHi - m - ls;
        *(float2*)&out[(size_t)node * DOUT + 2 * hl] = o;
    }
}

// ---------------------------------------------------------------------------
extern "C" void kernel_launch(void* const* d_in, const int* in_sizes, int n_in,
                              void* d_out, int out_size, void* d_ws, size_t ws_size,
                              hipStream_t stream) {
    const float* x     = (const float*)d_in[0];
    const int*   ei    = (const int*)d_in[1];
    const float* diags = (const float*)d_in[3];
    const float* W     = (const float*)d_in[4];
    const float* b     = (const float*)d_in[5];
    const float* m1    = (const float*)d_in[6];
    const float* m2    = (const float*)d_in[7];
    const float* m3    = (const float*)d_in[8];
    const float* e1    = (const float*)d_in[9];
    const float* e2    = (const float*)d_in[10];
    const float* e3    = (const float*)d_in[11];
    float* out = (float*)d_out;

    const int n = in_sizes[3];            // 100000
    const int e_cnt = in_sizes[1] / 2;    // 1600000
    const int nbk = (n + BK_COLS - 1) >> BK_SHIFT;          // 782 buckets
    const int chunk = (e_cnt + NBLK - 1) / NBLK;            // 25000 edges/chunk

    char* ws = (char*)d_ws;
    // --- small-matrix region (fixed offsets) ---
    float*    Wo   = (float*)ws;                 // 8192 floats = 32KB
    float*    S    = (float*)(ws + 32768);       // bjorck scratch: 13x4096 f
    // --- big arrays ---
    float*          d_e2m    = S + 53248;              // n
    float*          d_e3p    = d_e2m + n;              // n
    float*          gso2     = d_e3p + n;              // n
    unsigned short* xwb      = (unsigned short*)(gso2 + n);   // n*64 bf16
    int*            offsets  = (int*)(xwb + (size_t)n * DOUT); // n+4
    unsigned*       bucketed = (unsigned*)(offsets + n + 4);   // e_cnt
    unsigned*       blk_hist = bucketed + e_cnt;               // NBLK*1024
    unsigned*       boff     = blk_hist + (size_t)NBLK * NBK_STRIDE; // nbk+8
    uintptr_t pp = ((uintptr_t)(boff + nbk + 8) + 15) & ~(uintptr_t)15;
    uint2*          pairs    = (uint2*)pp;                     // e_cnt (8B)

    // ---- Bjorck chain: ONE narrow cooperative kernel -----------------------
    {
        void* args[] = { (void*)&W, (void*)&S, (void*)&Wo };
        hipLaunchCooperativeKernel((const void*)bjorck_coop, dim3(16), dim3(256),
                                   args, 0, stream);
    }
    // ---- node prep + feature transform ------------------------------------
    node_prep<<<(n + 255) / 256, 256, 0, stream>>>(diags, m1, m2, m3, e1, e2, e3,
                                                   d_e2m, d_e3p, gso2, n);
    xw_kernel<<<(n + XN - 1) / XN, 256, 0, stream>>>(x, Wo, xwb, n);
    // ---- two-level bucket sort -> CSR (separate kernels; proven) -----------
    b1_hist<<<NBLK, 256, 0, stream>>>(ei, blk_hist, e_cnt, chunk, nbk);
    s_scan<<<1, 1024, 0, stream>>>(blk_hist, boff, nbk, e_cnt);
    b2_scatter<<<NBLK, 256, 0, stream>>>(ei, blk_hist, bucketed, e_cnt, chunk, nbk);
    c_csr<<<nbk, 256, 0, stream>>>(bucketed, boff, d_e2m, offsets, pairs, n, e_cnt);
    // ---- fused gather + softmax --------------------------------------------
    gather_kernel<<<(n + 3) / 4, 256, 0, stream>>>(offsets, pairs, d_e3p,
                                                   xwb, gso2, b, out, n);
}

// Round 18
// 259.151 us; speedup vs baseline: 3.4219x; 1.2383x over previous
//
#include <hip/hip_runtime.h>
#include <math.h>

#define DIN 128
#define DOUT 64

#define NBLK 64             // binning blocks for hist/scatter (write locality)
#define BK_SHIFT 7          // 128 cols per bucket
#define BK_COLS 128
#define NBK_STRIDE 1024     // blk_hist row stride
#define CCAP 4096           // max edges per bucket staged in LDS (mean ~2046)

__device__ __forceinline__ float safe_pow(float d, float e) {
    float p = powf(d, e);
    return isinf(p) ? 0.0f : p;
}

__device__ __forceinline__ float dot4(float4 a, float4 b) {
    return a.x * b.x + a.y * b.y + a.z * b.z + a.w * b.w;
}

__device__ __forceinline__ unsigned short f32_to_bf16(float f) {
    unsigned bits = __float_as_uint(f);
    unsigned r = (bits + 0x7FFFu + ((bits >> 16) & 1u)) >> 16;
    return (unsigned short)r;
}

// ---------------------------------------------------------------------------
// Plain multi-block 64x64 matmul: C = A @ B, Bsrc SYMMETRIC (rows read as
// cols). grid 8 (single) or 16 (dual: blocks 8..15 compute C2 = A2 @ B).
// Optional CB output (single passes only): CB = 1.5I - 0.5*C.
// ROUND-17 LESSON: keep these as SEPARATE ~3µs launches — grid.sync() costs
// ~9µs each on MI355X, so cooperative fusion of this chain is a net loss.
// ---------------------------------------------------------------------------
__global__ __launch_bounds__(256) void mm_pass(const float* A1, const float* A2,
                                               const float* Bsrc,
                                               float* C1, float* C2, float* CB) {
    int t = threadIdx.x;
    bool second = (blockIdx.x >= 8);
    int blk = blockIdx.x & 7;
    const float* As = second ? A2 : A1;
    float* Cs = second ? C2 : C1;
    int c = t & 63;
    int r0 = blk * 8 + (t >> 6) * 2;
    float acc0 = 0.f, acc1 = 0.f;
#pragma unroll
    for (int k4 = 0; k4 < 16; ++k4) {
        float4 b  = *(const float4*)&Bsrc[c * 64 + k4 * 4];
        float4 a0 = *(const float4*)&As[r0 * 64 + k4 * 4];
        float4 a1 = *(const float4*)&As[(r0 + 1) * 64 + k4 * 4];
        acc0 += dot4(a0, b);
        acc1 += dot4(a1, b);
    }
    Cs[r0 * 64 + c] = acc0;
    Cs[(r0 + 1) * 64 + c] = acc1;
    if (CB != nullptr && !second) {
        CB[r0 * 64 + c]       = ((r0 == c)     ? 1.5f : 0.0f) - 0.5f * acc0;
        CB[(r0 + 1) * 64 + c] = ((r0 + 1 == c) ? 1.5f : 0.0f) - 0.5f * acc1;
    }
}

// ---------------------------------------------------------------------------
// G = W @ W^T (64x64, K=128), 8 blocks.
// ---------------------------------------------------------------------------
__global__ __launch_bounds__(256) void gram_pass(const float* W, float* G) {
    int t = threadIdx.x;
    int c = t & 63;
    int r0 = blockIdx.x * 8 + (t >> 6) * 2;
    float acc0 = 0.f, acc1 = 0.f;
#pragma unroll
    for (int k4 = 0; k4 < 32; ++k4) {
        float4 b  = *(const float4*)&W[c * 128 + k4 * 4];
        float4 a0 = *(const float4*)&W[r0 * 128 + k4 * 4];
        float4 a1 = *(const float4*)&W[(r0 + 1) * 128 + k4 * 4];
        acc0 += dot4(a0, b);
        acc1 += dot4(a1, b);
    }
    G[r0 * 64 + c] = acc0;
    G[(r0 + 1) * 64 + c] = acc1;
}

// ---------------------------------------------------------------------------
// power iteration on H2 = G^4 (trace-scaled, 8 raw iters + Rayleigh), 1 wave.
// ---------------------------------------------------------------------------
__global__ __launch_bounds__(64) void power_pass(const float* gH2, float* gSc) {
    int t = threadIdx.x;
    float tr = gH2[t * 65];
#pragma unroll
    for (int d = 1; d < 64; d <<= 1) tr += __shfl_xor(tr, d);
    float inv_tr = 1.0f / tr;
    float4 g4[16];
#pragma unroll
    for (int j4 = 0; j4 < 16; ++j4) {
        float4 v = *(const float4*)&gH2[t * 64 + j4 * 4];
        v.x *= inv_tr; v.y *= inv_tr; v.z *= inv_tr; v.w *= inv_tr;
        g4[j4] = v;
    }
    unsigned h = (unsigned)t * 2654435761u;
    float xv = 0.5f + (float)((h >> 17) & 0x7fff) * (1.0f / 32768.0f);
    float yv = 0.f;
    for (int it = 0; it < 8; ++it) {
        float p0 = 0.f, p1 = 0.f, p2 = 0.f, p3 = 0.f;
#pragma unroll
        for (int j4 = 0; j4 < 16; ++j4) {
            float4 xx;
            xx.x = __shfl(xv, j4 * 4 + 0);
            xx.y = __shfl(xv, j4 * 4 + 1);
            xx.z = __shfl(xv, j4 * 4 + 2);
            xx.w = __shfl(xv, j4 * 4 + 3);
            float dd = dot4(g4[j4], xx);
            if (j4 < 4) p0 += dd; else if (j4 < 8) p1 += dd;
            else if (j4 < 12) p2 += dd; else p3 += dd;
        }
        yv = (p0 + p1) + (p2 + p3);
        if (it < 7) xv = yv;
    }
    float num = xv * yv, den = xv * xv;
#pragma unroll
    for (int d = 1; d < 64; d <<= 1) {
        num += __shfl_xor(num, d);
        den += __shfl_xor(den, d);
    }
    if (t == 0) {
        float lam_h2 = tr * num / den;        // = sigma^8
        float sig = powf(lam_h2, 0.125f);
        gSc[0] = 1.0f / (1.1f * sig);
        gSc[1] = 1.0f / (1.21f * sig * sig);
    }
}

// ---------------------------------------------------------------------------
// prep: A0 = rs*G;  B0 = 1.5I - 0.5*A0
// ---------------------------------------------------------------------------
__global__ __launch_bounds__(256) void prep_pass(const float* gG, const float* gSc,
                                                 float* gA0, float* gB0) {
    int idx = blockIdx.x * 256 + threadIdx.x;
    if (idx >= 4096) return;
    float rs = gSc[1];
    int r = idx >> 6, c = idx & 63;
    float a0 = rs * gG[idx];
    gA0[idx] = a0;
    gB0[idx] = ((r == c) ? 1.5f : 0.0f) - 0.5f * a0;
}

// ---------------------------------------------------------------------------
// Wo = sc * P @ W  (64x128), 8 blocks.
// ---------------------------------------------------------------------------
__global__ __launch_bounds__(256) void wo_pass(const float* W, const float* P,
                                               const float* gSc, float* Wo) {
    int t = threadIdx.x;
    int c = t & 63;
    int r0 = blockIdx.x * 8 + (t >> 6) * 2;
    float a00 = 0.f, a01 = 0.f, a10 = 0.f, a11 = 0.f;
#pragma unroll 4
    for (int j = 0; j < 64; ++j) {
        float p0 = P[r0 * 64 + j];
        float p1 = P[(r0 + 1) * 64 + j];
        float w0 = W[j * 128 + c];
        float w1 = W[j * 128 + c + 64];
        a00 += p0 * w0; a01 += p0 * w1;
        a10 += p1 * w0; a11 += p1 * w1;
    }
    float sc = gSc[0];
    Wo[r0 * 128 + c]            = sc * a00;
    Wo[r0 * 128 + c + 64]       = sc * a01;
    Wo[(r0 + 1) * 128 + c]      = sc * a10;
    Wo[(r0 + 1) * 128 + c + 64] = sc * a11;
}

// ---------------------------------------------------------------------------
// per-node prep
// ---------------------------------------------------------------------------
__global__ void node_prep(const float* __restrict__ diags,
                          const float* m1, const float* m2, const float* m3,
                          const float* e1, const float* e2, const float* e3,
                          float* __restrict__ d_e2m, float* __restrict__ d_e3p,
                          float* __restrict__ gso2, int n) {
    int i = blockIdx.x * blockDim.x + threadIdx.x;
    if (i >= n) return;
    float d = diags[i];
    float p1 = safe_pow(d, e1[0]);
    float p2 = safe_pow(d, e2[0]);
    float p3 = safe_pow(d, e3[0]);
    float vm2 = m2[0];
    d_e2m[i] = vm2 * p2;
    d_e3p[i] = p3;
    gso2[i] = m1[0] * p1 + vm2 * p2 * p3 + m3[0];
}

// ---------------------------------------------------------------------------
// xw = x @ Wo^T — register-tiled GEMM; OUTPUT IN BF16.
// ---------------------------------------------------------------------------
#define XN 64
#define XS 132
__global__ __launch_bounds__(256) void xw_kernel(const float* __restrict__ x,
                                                 const float* __restrict__ Wo,
                                                 unsigned short* __restrict__ xwb,
                                                 int n) {
    __shared__ __align__(16) float xs[XN * XS];
    __shared__ __align__(16) float ws[DOUT * XS];
    int t = threadIdx.x;
    int base = blockIdx.x * XN;
    for (int f = t; f < DOUT * (DIN / 4); f += 256) {
        int r = f >> 5, c = f & 31;
        *(float4*)&ws[r * XS + c * 4] = *(const float4*)&Wo[r * DIN + c * 4];
    }
    for (int f = t; f < XN * (DIN / 4); f += 256) {
        int r = f >> 5, c = f & 31;
        int node = base + r;
        float4 v = make_float4(0.f, 0.f, 0.f, 0.f);
        if (node < n) v = *(const float4*)&x[(size_t)node * DIN + c * 4];
        *(float4*)&xs[r * XS + c * 4] = v;
    }
    __syncthreads();
    int tn = t >> 4;
    int td = t & 15;
    float acc[4][4] = {};
#pragma unroll 2
    for (int k4 = 0; k4 < DIN / 4; ++k4) {
        float4 a[4], w[4];
#pragma unroll
        for (int r = 0; r < 4; ++r) a[r] = *(const float4*)&xs[(tn * 4 + r) * XS + k4 * 4];
#pragma unroll
        for (int c = 0; c < 4; ++c) w[c] = *(const float4*)&ws[(td + c * 16) * XS + k4 * 4];
#pragma unroll
        for (int r = 0; r < 4; ++r)
#pragma unroll
            for (int c = 0; c < 4; ++c) acc[r][c] += dot4(a[r], w[c]);
    }
#pragma unroll
    for (int r = 0; r < 4; ++r) {
        int node = base + tn * 4 + r;
        if (node >= n) break;
#pragma unroll
        for (int c = 0; c < 4; ++c)
            xwb[(size_t)node * DOUT + td + c * 16] = f32_to_bf16(acc[r][c]);
    }
}

// ---------------------------------------------------------------------------
// Sort pass B1: per-block bucket histograms (bucket = col >> 7).
// ---------------------------------------------------------------------------
__global__ __launch_bounds__(256) void b1_hist(const int* __restrict__ ei,
                                               unsigned* __restrict__ blk_hist,
                                               int e_cnt, int chunk, int nbk) {
    __shared__ int h[NBK_STRIDE];
    int b = blockIdx.x, t = threadIdx.x;
    for (int j = t; j < NBK_STRIDE; j += 256) h[j] = 0;
    __syncthreads();
    int lo = b * chunk, hi = min(lo + chunk, e_cnt);
    for (int e = lo + t; e < hi; e += 256)
        atomicAdd(&h[ei[e_cnt + e] >> BK_SHIFT], 1);
    __syncthreads();
    for (int j = t; j < nbk; j += 256)
        blk_hist[(size_t)b * NBK_STRIDE + j] = (unsigned)h[j];
}

// ---------------------------------------------------------------------------
// Sort pass S: scan bucket totals -> bucket_offsets + per-(block,bucket) bases.
// ---------------------------------------------------------------------------
__global__ __launch_bounds__(1024) void s_scan(unsigned* __restrict__ blk_hist,
                                               unsigned* __restrict__ bucket_offsets,
                                               int nbk, int e_cnt) {
    __shared__ int tot[1024];
    int t = threadIdx.x;
    int total = 0;
    if (t < nbk) {
        int run = 0;
        for (int b = 0; b < NBLK; ++b) {
            size_t idx = (size_t)b * NBK_STRIDE + t;
            int v = (int)blk_hist[idx];
            blk_hist[idx] = (unsigned)run;
            run += v;
        }
        total = run;
    }
    tot[t] = total;
    __syncthreads();
    for (int d = 1; d < 1024; d <<= 1) {
        int u = (t >= d) ? tot[t - d] : 0;
        __syncthreads();
        tot[t] += u;
        __syncthreads();
    }
    int excl = tot[t] - total;
    if (t < nbk) {
        bucket_offsets[t] = (unsigned)excl;
        for (int b = 0; b < NBLK; ++b)
            blk_hist[(size_t)b * NBK_STRIDE + t] += (unsigned)excl;
    }
    if (t == 0) bucket_offsets[nbk] = (unsigned)e_cnt;
}

// ---------------------------------------------------------------------------
// Sort pass B2: scatter packed (src<<7 | lcol) into reserved per-block runs.
// ---------------------------------------------------------------------------
__global__ __launch_bounds__(256) void b2_scatter(const int* __restrict__ ei,
                                                  const unsigned* __restrict__ blk_hist,
                                                  unsigned* __restrict__ bucketed,
                                                  int e_cnt, int chunk, int nbk) {
    __shared__ int cur[NBK_STRIDE];
    int b = blockIdx.x, t = threadIdx.x;
    for (int j = t; j < nbk; j += 256)
        cur[j] = (int)blk_hist[(size_t)b * NBK_STRIDE + j];
    __syncthreads();
    int lo = b * chunk, hi = min(lo + chunk, e_cnt);
    for (int e = lo + t; e < hi; e += 256) {
        int col = ei[e_cnt + e];
        int src = ei[e];
        int bkt = col >> BK_SHIFT;
        int pos = atomicAdd(&cur[bkt], 1);
        bucketed[pos] = ((unsigned)src << BK_SHIFT) | (unsigned)(col & (BK_COLS - 1));
    }
}

// ---------------------------------------------------------------------------
// Sort pass C: one block per bucket -> exact CSR + (src, weight_f32) pairs.
// ---------------------------------------------------------------------------
__global__ __launch_bounds__(256) void c_csr(const unsigned* __restrict__ bucketed,
                                             const unsigned* __restrict__ bucket_offsets,
                                             const float* __restrict__ d_e2m,
                                             int* __restrict__ offsets,
                                             uint2* __restrict__ pairs,
                                             int n, int e_cnt) {
    __shared__ unsigned sE[CCAP];
    __shared__ int sh[BK_COLS];
    __shared__ int sc[BK_COLS];
    __shared__ int pos_[BK_COLS];
    int b = blockIdx.x, t = threadIdx.x;
    int base = (int)bucket_offsets[b];
    int cnt = (int)bucket_offsets[b + 1] - base;
    bool fits = (cnt <= CCAP);
    if (fits)
        for (int i = t; i < cnt; i += 256) sE[i] = bucketed[base + i];
    if (t < BK_COLS) sh[t] = 0;
    __syncthreads();
    for (int i = t; i < cnt; i += 256) {
        unsigned p = fits ? sE[i] : bucketed[base + i];
        atomicAdd(&sh[p & (BK_COLS - 1)], 1);
    }
    __syncthreads();
    if (t < BK_COLS) sc[t] = sh[t];
    __syncthreads();
    for (int d = 1; d < BK_COLS; d <<= 1) {
        int u = 0;
        if (t < BK_COLS && t >= d) u = sc[t - d];
        __syncthreads();
        if (t < BK_COLS) sc[t] += u;
        __syncthreads();
    }
    if (t < BK_COLS) {
        int pre = sc[t] - sh[t];
        int gc = b * BK_COLS + t;
        if (gc < n) offsets[gc] = base + pre;
        pos_[t] = pre;
    }
    if (b == 0 && t == 0) offsets[n] = e_cnt;
    __syncthreads();
    for (int i = t; i < cnt; i += 256) {
        unsigned p = fits ? sE[i] : bucketed[base + i];
        int lc = (int)(p & (BK_COLS - 1));
        unsigned s = p >> BK_SHIFT;
        int q = atomicAdd(&pos_[lc], 1);
        uint2 o;
        o.x = s;
        o.y = __float_as_uint(d_e2m[s]);
        pairs[base + q] = o;
    }
}

// ---------------------------------------------------------------------------
// fused gather + self-loop + bias + log-softmax; one wave per node.
// DWORD-PACKED (round-17, ~20µs better than ushort version): each lane loads
// one uint (2 bf16 dims); lanes 0-31 cover the row, the two wave-halves
// process two edges per load instruction.
// ---------------------------------------------------------------------------
__global__ __launch_bounds__(256) void gather_kernel(const int* __restrict__ offsets,
                                                     const uint2* __restrict__ pairs,
                                                     const float* __restrict__ d_e3p,
                                                     const unsigned short* __restrict__ xwb,
                                                     const float* __restrict__ gso2,
                                                     const float* __restrict__ b,
                                                     float* __restrict__ out, int n) {
    unsigned lane = threadIdx.x & 63;
    unsigned half = lane >> 5;          // 0 or 1
    unsigned hl = lane & 31;            // dword index within the 64-dim row
    int node = blockIdx.x * 4 + (threadIdx.x >> 6);
    if (node >= n) return;
    int lo = offsets[node], hi = offsets[node + 1];
    const unsigned* xw32 = (const unsigned*)xwb;   // row stride 32 dwords
    float accLo = 0.f, accHi = 0.f;
    int i = lo;
    for (; i + 8 <= hi; i += 8) {
        int e0 = i + 4 * half;
        uint2 p0 = pairs[e0 + 0], p1 = pairs[e0 + 1];
        uint2 p2 = pairs[e0 + 2], p3 = pairs[e0 + 3];
        unsigned u0 = xw32[p0.x * 32u + hl];
        unsigned u1 = xw32[p1.x * 32u + hl];
        unsigned u2 = xw32[p2.x * 32u + hl];
        unsigned u3 = xw32[p3.x * 32u + hl];
        float w0 = __uint_as_float(p0.y), w1 = __uint_as_float(p1.y);
        float w2 = __uint_as_float(p2.y), w3 = __uint_as_float(p3.y);
        accLo += w0 * __uint_as_float(u0 << 16) + w1 * __uint_as_float(u1 << 16)
               + w2 * __uint_as_float(u2 << 16) + w3 * __uint_as_float(u3 << 16);
        accHi += w0 * __uint_as_float(u0 & 0xFFFF0000u) + w1 * __uint_as_float(u1 & 0xFFFF0000u)
               + w2 * __uint_as_float(u2 & 0xFFFF0000u) + w3 * __uint_as_float(u3 & 0xFFFF0000u);
    }
    for (; i + 4 <= hi; i += 4) {
        int e0 = i + 2 * half;
        uint2 p0 = pairs[e0 + 0], p1 = pairs[e0 + 1];
        unsigned u0 = xw32[p0.x * 32u + hl];
        unsigned u1 = xw32[p1.x * 32u + hl];
        float w0 = __uint_as_float(p0.y), w1 = __uint_as_float(p1.y);
        accLo += w0 * __uint_as_float(u0 << 16) + w1 * __uint_as_float(u1 << 16);
        accHi += w0 * __uint_as_float(u0 & 0xFFFF0000u) + w1 * __uint_as_float(u1 & 0xFFFF0000u);
    }
    {
        int rem = hi - i;
        int j0 = 2 * (int)half;
        int j1 = min(j0 + 2, rem);
        for (int j = j0; j < j1; ++j) {
            uint2 p = pairs[i + j];
            unsigned u = xw32[p.x * 32u + hl];
            float w = __uint_as_float(p.y);
            accLo += w * __uint_as_float(u << 16);
            accHi += w * __uint_as_float(u & 0xFFFF0000u);
        }
    }
    accLo += __shfl_xor(accLo, 32);
    accHi += __shfl_xor(accHi, 32);

    unsigned us = xw32[(unsigned)node * 32u + hl];
    float xsLo = __uint_as_float(us << 16);
    float xsHi = __uint_as_float(us & 0xFFFF0000u);
    float2 bb = *(const float2*)&b[2 * hl];
    float gs = gso2[node], dn = d_e3p[node];
    float vLo = gs * xsLo + 2.0f * bb.x + dn * accLo;
    float vHi = gs * xsHi + 2.0f * bb.y + dn * accHi;
    float m = fmaxf(vLo, vHi);
#pragma unroll
    for (int d = 1; d < 32; d <<= 1) m = fmaxf(m, __shfl_xor(m, d));
    float s = expf(vLo - m) + expf(vHi - m);
#pragma unroll
    for (int d = 1; d < 32; d <<= 1) s += __shfl_xor(s, d);
    if (half == 0) {
        float ls = logf(s);
        float2 o;
        o.x = vLo - m - ls;
        o.y = vHi - m - ls;
        *(float2*)&out[(size_t)node * DOUT + 2 * hl] = o;
    }
}

// ---------------------------------------------------------------------------
extern "C" void kernel_launch(void* const* d_in, const int* in_sizes, int n_in,
                              void* d_out, int out_size, void* d_ws, size_t ws_size,
                              hipStream_t stream) {
    const float* x     = (const float*)d_in[0];
    const int*   ei    = (const int*)d_in[1];
    const float* diags = (const float*)d_in[3];
    const float* W     = (const float*)d_in[4];
    const float* b     = (const float*)d_in[5];
    const float* m1    = (const float*)d_in[6];
    const float* m2    = (const float*)d_in[7];
    const float* m3    = (const float*)d_in[8];
    const float* e1    = (const float*)d_in[9];
    const float* e2    = (const float*)d_in[10];
    const float* e3    = (const float*)d_in[11];
    float* out = (float*)d_out;

    const int n = in_sizes[3];            // 100000
    const int e_cnt = in_sizes[1] / 2;    // 1600000
    const int nbk = (n + BK_COLS - 1) >> BK_SHIFT;          // 782 buckets
    const int chunk = (e_cnt + NBLK - 1) / NBLK;            // 25000 edges/chunk

    char* ws = (char*)d_ws;
    // --- small-matrix region (fixed offsets) ---
    float*    Wo   = (float*)ws;                 // 8192 floats = 32KB
    float*    gG   = (float*)(ws + 32768);       // 12 x 4096 floats
    float*    gT   = gG  + 4096;
    float*    gA   = gT  + 4096;
    float*    gAn  = gA  + 4096;
    float*    gA0  = gAn + 4096;
    float*    gP   = gA0 + 4096;
    float*    gPn  = gP  + 4096;
    float*    gB0  = gPn + 4096;
    float*    gB1  = gB0 + 4096;
    float*    gB2  = gB1 + 4096;
    float*    gB3  = gB2 + 4096;
    float*    gB4  = gB3 + 4096;
    float*    gSc  = gB4 + 4096;                 // 2 floats (pad to 64)
    // --- big arrays ---
    float*          d_e2m    = gSc + 64;               // n
    float*          d_e3p    = d_e2m + n;              // n
    float*          gso2     = d_e3p + n;              // n
    unsigned short* xwb      = (unsigned short*)(gso2 + n);   // n*64 bf16
    int*            offsets  = (int*)(xwb + (size_t)n * DOUT); // n+4
    unsigned*       bucketed = (unsigned*)(offsets + n + 4);   // e_cnt
    unsigned*       blk_hist = bucketed + e_cnt;               // NBLK*1024
    unsigned*       boff     = blk_hist + (size_t)NBLK * NBK_STRIDE; // nbk+8
    uintptr_t pp = ((uintptr_t)(boff + nbk + 8) + 15) & ~(uintptr_t)15;
    uint2*          pairs    = (uint2*)pp;                     // e_cnt (8B)

    // ---- Bjorck chain: 15 small multi-block dispatches (proven ~45µs) ------
    gram_pass<<<8, 256, 0, stream>>>(W, gG);                              // G
    mm_pass<<<8, 256, 0, stream>>>(gG, nullptr, gG, gT, nullptr, nullptr); // H = G^2
    mm_pass<<<8, 256, 0, stream>>>(gT, nullptr, gT, gA, nullptr, nullptr); // H2 = G^4
    power_pass<<<1, 64, 0, stream>>>(gA, gSc);                            // sc, rs
    prep_pass<<<16, 256, 0, stream>>>(gG, gSc, gA0, gB0);                 // A0, B0
    mm_pass<<<8, 256, 0, stream>>>(gA0, nullptr, gB0, gT, nullptr, nullptr); // T = A0@B0
    mm_pass<<<8, 256, 0, stream>>>(gT, nullptr, gB0, gA, nullptr, gB1);   // A1 (+B1)
    mm_pass<<<16, 256, 0, stream>>>(gB0, gA, gB1, gP, gT, nullptr);       // P=B0B1, T=A1B1
    mm_pass<<<8, 256, 0, stream>>>(gT, nullptr, gB1, gAn, nullptr, gB2);  // A2 (+B2)
    mm_pass<<<16, 256, 0, stream>>>(gP, gAn, gB2, gPn, gT, nullptr);      // P=PB2, T=A2B2
    mm_pass<<<8, 256, 0, stream>>>(gT, nullptr, gB2, gA, nullptr, gB3);   // A3 (+B3)
    mm_pass<<<16, 256, 0, stream>>>(gPn, gA, gB3, gP, gT, nullptr);       // P=PB3, T=A3B3
    mm_pass<<<8, 256, 0, stream>>>(gT, nullptr, gB3, gAn, nullptr, gB4);  // A4 (+B4)
    mm_pass<<<8, 256, 0, stream>>>(gP, nullptr, gB4, gPn, nullptr, nullptr); // P final
    wo_pass<<<8, 256, 0, stream>>>(W, gPn, gSc, Wo);                      // Wo

    // ---- node prep + feature transform ------------------------------------
    node_prep<<<(n + 255) / 256, 256, 0, stream>>>(diags, m1, m2, m3, e1, e2, e3,
                                                   d_e2m, d_e3p, gso2, n);
    xw_kernel<<<(n + XN - 1) / XN, 256, 0, stream>>>(x, Wo, xwb, n);
    // ---- two-level bucket sort -> CSR --------------------------------------
    b1_hist<<<NBLK, 256, 0, stream>>>(ei, blk_hist, e_cnt, chunk, nbk);
    s_scan<<<1, 1024, 0, stream>>>(blk_hist, boff, nbk, e_cnt);
    b2_scatter<<<NBLK, 256, 0, stream>>>(ei, blk_hist, bucketed, e_cnt, chunk, nbk);
    c_csr<<<nbk, 256, 0, stream>>>(bucketed, boff, d_e2m, offsets, pairs, n, e_cnt);
    // ---- fused gather + softmax --------------------------------------------
    gather_kernel<<<(n + 3) / 4, 256, 0, stream>>>(offsets, pairs, d_e3p,
                                                   xwb, gso2, b, out, n);
}

// Round 19
// 254.808 us; speedup vs baseline: 3.4802x; 1.0170x over previous
//
#include <hip/hip_runtime.h>
#include <math.h>

#define DIN 128
#define DOUT 64

#define NBLK 64             // binning blocks for hist/scatter (write locality)
#define BK_SHIFT 7          // 128 cols per bucket
#define BK_COLS 128
#define NBK_STRIDE 1024     // blk_hist row stride
#define CCAP 3072           // max edges per bucket staged in LDS (mean ~2046, max ~2205)

__device__ __forceinline__ float safe_pow(float d, float e) {
    float p = powf(d, e);
    return isinf(p) ? 0.0f : p;
}

__device__ __forceinline__ float dot4(float4 a, float4 b) {
    return a.x * b.x + a.y * b.y + a.z * b.z + a.w * b.w;
}

__device__ __forceinline__ unsigned short f32_to_bf16(float f) {
    unsigned bits = __float_as_uint(f);
    unsigned r = (bits + 0x7FFFu + ((bits >> 16) & 1u)) >> 16;
    return (unsigned short)r;
}

// ---------------------------------------------------------------------------
// Plain multi-block 64x64 matmul (8/16 blocks). B SYMMETRIC (rows as cols).
// Optional CB = 1.5I - 0.5*C. Separate ~3µs launches (grid.sync costs ~9µs).
// ---------------------------------------------------------------------------
__global__ __launch_bounds__(256) void mm_pass(const float* A1, const float* A2,
                                               const float* Bsrc,
                                               float* C1, float* C2, float* CB) {
    int t = threadIdx.x;
    bool second = (blockIdx.x >= 8);
    int blk = blockIdx.x & 7;
    const float* As = second ? A2 : A1;
    float* Cs = second ? C2 : C1;
    int c = t & 63;
    int r0 = blk * 8 + (t >> 6) * 2;
    float acc0 = 0.f, acc1 = 0.f;
#pragma unroll
    for (int k4 = 0; k4 < 16; ++k4) {
        float4 b  = *(const float4*)&Bsrc[c * 64 + k4 * 4];
        float4 a0 = *(const float4*)&As[r0 * 64 + k4 * 4];
        float4 a1 = *(const float4*)&As[(r0 + 1) * 64 + k4 * 4];
        acc0 += dot4(a0, b);
        acc1 += dot4(a1, b);
    }
    Cs[r0 * 64 + c] = acc0;
    Cs[(r0 + 1) * 64 + c] = acc1;
    if (CB != nullptr && !second) {
        CB[r0 * 64 + c]       = ((r0 == c)     ? 1.5f : 0.0f) - 0.5f * acc0;
        CB[(r0 + 1) * 64 + c] = ((r0 + 1 == c) ? 1.5f : 0.0f) - 0.5f * acc1;
    }
}

// ---------------------------------------------------------------------------
// G = W @ W^T (64x64, K=128), 8 blocks.
// ---------------------------------------------------------------------------
__global__ __launch_bounds__(256) void gram_pass(const float* W, float* G) {
    int t = threadIdx.x;
    int c = t & 63;
    int r0 = blockIdx.x * 8 + (t >> 6) * 2;
    float acc0 = 0.f, acc1 = 0.f;
#pragma unroll
    for (int k4 = 0; k4 < 32; ++k4) {
        float4 b  = *(const float4*)&W[c * 128 + k4 * 4];
        float4 a0 = *(const float4*)&W[r0 * 128 + k4 * 4];
        float4 a1 = *(const float4*)&W[(r0 + 1) * 128 + k4 * 4];
        acc0 += dot4(a0, b);
        acc1 += dot4(a1, b);
    }
    G[r0 * 64 + c] = acc0;
    G[(r0 + 1) * 64 + c] = acc1;
}

// ---------------------------------------------------------------------------
// power iteration on H2 = G^4 (wave 0) + prep A0 = rs*G, B0 = 1.5I - 0.5*A0
// (all 256 threads). Merged to save a launch.
// ---------------------------------------------------------------------------
__global__ __launch_bounds__(256) void power_prep(const float* gH2, const float* gG,
                                                  float* gSc, float* gA0, float* gB0) {
    __shared__ float sS[2];
    int t = threadIdx.x;
    if (t < 64) {
        float tr = gH2[t * 65];
#pragma unroll
        for (int d = 1; d < 64; d <<= 1) tr += __shfl_xor(tr, d);
        float inv_tr = 1.0f / tr;
        float4 g4[16];
#pragma unroll
        for (int j4 = 0; j4 < 16; ++j4) {
            float4 v = *(const float4*)&gH2[t * 64 + j4 * 4];
            v.x *= inv_tr; v.y *= inv_tr; v.z *= inv_tr; v.w *= inv_tr;
            g4[j4] = v;
        }
        unsigned h = (unsigned)t * 2654435761u;
        float xv = 0.5f + (float)((h >> 17) & 0x7fff) * (1.0f / 32768.0f);
        float yv = 0.f;
        for (int it = 0; it < 8; ++it) {
            float p0 = 0.f, p1 = 0.f, p2 = 0.f, p3 = 0.f;
#pragma unroll
            for (int j4 = 0; j4 < 16; ++j4) {
                float4 xx;
                xx.x = __shfl(xv, j4 * 4 + 0);
                xx.y = __shfl(xv, j4 * 4 + 1);
                xx.z = __shfl(xv, j4 * 4 + 2);
                xx.w = __shfl(xv, j4 * 4 + 3);
                float dd = dot4(g4[j4], xx);
                if (j4 < 4) p0 += dd; else if (j4 < 8) p1 += dd;
                else if (j4 < 12) p2 += dd; else p3 += dd;
            }
            yv = (p0 + p1) + (p2 + p3);
            if (it < 7) xv = yv;
        }
        float num = xv * yv, den = xv * xv;
#pragma unroll
        for (int d = 1; d < 64; d <<= 1) {
            num += __shfl_xor(num, d);
            den += __shfl_xor(den, d);
        }
        if (t == 0) {
            float lam_h2 = tr * num / den;        // = sigma^8
            float sig = powf(lam_h2, 0.125f);
            float sc = 1.0f / (1.1f * sig);
            float rs = 1.0f / (1.21f * sig * sig);
            gSc[0] = sc; gSc[1] = rs;
            sS[0] = sc; sS[1] = rs;
        }
    }
    __syncthreads();
    float rs = sS[1];
    for (int idx = t; idx < 4096; idx += 256) {
        int r = idx >> 6, c2 = idx & 63;
        float a0 = rs * gG[idx];
        gA0[idx] = a0;
        gB0[idx] = ((r == c2) ? 1.5f : 0.0f) - 0.5f * a0;
    }
}

// ---------------------------------------------------------------------------
// Wo = sc * P @ W  (64x128), 8 blocks.
// ---------------------------------------------------------------------------
__global__ __launch_bounds__(256) void wo_pass(const float* W, const float* P,
                                               const float* gSc, float* Wo) {
    int t = threadIdx.x;
    int c = t & 63;
    int r0 = blockIdx.x * 8 + (t >> 6) * 2;
    float a00 = 0.f, a01 = 0.f, a10 = 0.f, a11 = 0.f;
#pragma unroll 4
    for (int j = 0; j < 64; ++j) {
        float p0 = P[r0 * 64 + j];
        float p1 = P[(r0 + 1) * 64 + j];
        float w0 = W[j * 128 + c];
        float w1 = W[j * 128 + c + 64];
        a00 += p0 * w0; a01 += p0 * w1;
        a10 += p1 * w0; a11 += p1 * w1;
    }
    float sc = gSc[0];
    Wo[r0 * 128 + c]            = sc * a00;
    Wo[r0 * 128 + c + 64]       = sc * a01;
    Wo[(r0 + 1) * 128 + c]      = sc * a10;
    Wo[(r0 + 1) * 128 + c + 64] = sc * a11;
}

// ---------------------------------------------------------------------------
// per-node prep
// ---------------------------------------------------------------------------
__global__ void node_prep(const float* __restrict__ diags,
                          const float* m1, const float* m2, const float* m3,
                          const float* e1, const float* e2, const float* e3,
                          float* __restrict__ d_e2m, float* __restrict__ d_e3p,
                          float* __restrict__ gso2, int n) {
    int i = blockIdx.x * blockDim.x + threadIdx.x;
    if (i >= n) return;
    float d = diags[i];
    float p1 = safe_pow(d, e1[0]);
    float p2 = safe_pow(d, e2[0]);
    float p3 = safe_pow(d, e3[0]);
    float vm2 = m2[0];
    d_e2m[i] = vm2 * p2;
    d_e3p[i] = p3;
    gso2[i] = m1[0] * p1 + vm2 * p2 * p3 + m3[0];
}

// ---------------------------------------------------------------------------
// xw = x @ Wo^T — register-tiled GEMM; OUTPUT IN BF16.
// ---------------------------------------------------------------------------
#define XN 64
#define XS 132
__global__ __launch_bounds__(256) void xw_kernel(const float* __restrict__ x,
                                                 const float* __restrict__ Wo,
                                                 unsigned short* __restrict__ xwb,
                                                 int n) {
    __shared__ __align__(16) float xs[XN * XS];
    __shared__ __align__(16) float ws[DOUT * XS];
    int t = threadIdx.x;
    int base = blockIdx.x * XN;
    for (int f = t; f < DOUT * (DIN / 4); f += 256) {
        int r = f >> 5, c = f & 31;
        *(float4*)&ws[r * XS + c * 4] = *(const float4*)&Wo[r * DIN + c * 4];
    }
    for (int f = t; f < XN * (DIN / 4); f += 256) {
        int r = f >> 5, c = f & 31;
        int node = base + r;
        float4 v = make_float4(0.f, 0.f, 0.f, 0.f);
        if (node < n) v = *(const float4*)&x[(size_t)node * DIN + c * 4];
        *(float4*)&xs[r * XS + c * 4] = v;
    }
    __syncthreads();
    int tn = t >> 4;
    int td = t & 15;
    float acc[4][4] = {};
#pragma unroll 2
    for (int k4 = 0; k4 < DIN / 4; ++k4) {
        float4 a[4], w[4];
#pragma unroll
        for (int r = 0; r < 4; ++r) a[r] = *(const float4*)&xs[(tn * 4 + r) * XS + k4 * 4];
#pragma unroll
        for (int c = 0; c < 4; ++c) w[c] = *(const float4*)&ws[(td + c * 16) * XS + k4 * 4];
#pragma unroll
        for (int r = 0; r < 4; ++r)
#pragma unroll
            for (int c = 0; c < 4; ++c) acc[r][c] += dot4(a[r], w[c]);
    }
#pragma unroll
    for (int r = 0; r < 4; ++r) {
        int node = base + tn * 4 + r;
        if (node >= n) break;
#pragma unroll
        for (int c = 0; c < 4; ++c)
            xwb[(size_t)node * DOUT + td + c * 16] = f32_to_bf16(acc[r][c]);
    }
}

// ---------------------------------------------------------------------------
// Sort pass B1: per-block bucket histograms (bucket = col >> 7).
// ---------------------------------------------------------------------------
__global__ __launch_bounds__(256) void b1_hist(const int* __restrict__ ei,
                                               unsigned* __restrict__ blk_hist,
                                               int e_cnt, int chunk, int nbk) {
    __shared__ int h[NBK_STRIDE];
    int b = blockIdx.x, t = threadIdx.x;
    for (int j = t; j < NBK_STRIDE; j += 256) h[j] = 0;
    __syncthreads();
    int lo = b * chunk, hi = min(lo + chunk, e_cnt);
    for (int e = lo + t; e < hi; e += 256)
        atomicAdd(&h[ei[e_cnt + e] >> BK_SHIFT], 1);
    __syncthreads();
    for (int j = t; j < nbk; j += 256)
        blk_hist[(size_t)b * NBK_STRIDE + j] = (unsigned)h[j];
}

// ---------------------------------------------------------------------------
// Sort pass S: scan bucket totals -> bucket_offsets + per-(block,bucket) bases.
// ---------------------------------------------------------------------------
__global__ __launch_bounds__(1024) void s_scan(unsigned* __restrict__ blk_hist,
                                               unsigned* __restrict__ bucket_offsets,
                                               int nbk, int e_cnt) {
    __shared__ int tot[1024];
    int t = threadIdx.x;
    int total = 0;
    if (t < nbk) {
        int run = 0;
        for (int b = 0; b < NBLK; ++b) {
            size_t idx = (size_t)b * NBK_STRIDE + t;
            int v = (int)blk_hist[idx];
            blk_hist[idx] = (unsigned)run;
            run += v;
        }
        total = run;
    }
    tot[t] = total;
    __syncthreads();
    for (int d = 1; d < 1024; d <<= 1) {
        int u = (t >= d) ? tot[t - d] : 0;
        __syncthreads();
        tot[t] += u;
        __syncthreads();
    }
    int excl = tot[t] - total;
    if (t < nbk) {
        bucket_offsets[t] = (unsigned)excl;
        for (int b = 0; b < NBLK; ++b)
            blk_hist[(size_t)b * NBK_STRIDE + t] += (unsigned)excl;
    }
    if (t == 0) bucket_offsets[nbk] = (unsigned)e_cnt;
}

// ---------------------------------------------------------------------------
// Sort pass B2: scatter packed (src<<7 | lcol) into reserved per-block runs.
// ---------------------------------------------------------------------------
__global__ __launch_bounds__(256) void b2_scatter(const int* __restrict__ ei,
                                                  const unsigned* __restrict__ blk_hist,
                                                  unsigned* __restrict__ bucketed,
                                                  int e_cnt, int chunk, int nbk) {
    __shared__ int cur[NBK_STRIDE];
    int b = blockIdx.x, t = threadIdx.x;
    for (int j = t; j < nbk; j += 256)
        cur[j] = (int)blk_hist[(size_t)b * NBK_STRIDE + j];
    __syncthreads();
    int lo = b * chunk, hi = min(lo + chunk, e_cnt);
    for (int e = lo + t; e < hi; e += 256) {
        int col = ei[e_cnt + e];
        int src = ei[e];
        int bkt = col >> BK_SHIFT;
        int pos = atomicAdd(&cur[bkt], 1);
        bucketed[pos] = ((unsigned)src << BK_SHIFT) | (unsigned)(col & (BK_COLS - 1));
    }
}

// ---------------------------------------------------------------------------
// FUSED per-bucket CSR sort + gather + self-loop + bias + log-softmax.
// One 512-thread block per bucket: counting-sort the bucket's (src, w) pairs
// into LDS (no pairs global round-trip), then 8 waves gather 16 nodes each
// with the round-17 dword scheme, pair metadata from LDS broadcast.
// Spill path (cnt > CCAP, never taken for this data) keeps correctness.
// ---------------------------------------------------------------------------
__global__ __launch_bounds__(512) void csr_gather(const unsigned* __restrict__ bucketed,
                                                  const unsigned* __restrict__ boff,
                                                  const float* __restrict__ d_e2m,
                                                  const float* __restrict__ d_e3p,
                                                  const unsigned short* __restrict__ xwb,
                                                  const float* __restrict__ gso2,
                                                  const float* __restrict__ bias,
                                                  uint2* __restrict__ spill,
                                                  float* __restrict__ out, int n) {
    __shared__ __align__(16) uint2 sP[CCAP];
    __shared__ int shc[BK_COLS], scc[BK_COLS], posc[BK_COLS];
    __shared__ int offs[BK_COLS + 1];
    int b = blockIdx.x, t = threadIdx.x;
    int base = (int)boff[b];
    int cnt = (int)boff[b + 1] - base;
    bool fits = (cnt <= CCAP);

    if (t < BK_COLS) shc[t] = 0;
    __syncthreads();
    for (int i = t; i < cnt; i += 512)
        atomicAdd(&shc[bucketed[base + i] & (BK_COLS - 1)], 1);
    __syncthreads();
    if (t < BK_COLS) scc[t] = shc[t];
    __syncthreads();
    for (int d = 1; d < BK_COLS; d <<= 1) {
        int u = 0;
        if (t < BK_COLS && t >= d) u = scc[t - d];
        __syncthreads();
        if (t < BK_COLS) scc[t] += u;
        __syncthreads();
    }
    if (t < BK_COLS) {
        int pre = scc[t] - shc[t];
        posc[t] = pre;
        offs[t] = pre;
    }
    if (t == 0) offs[BK_COLS] = cnt;
    __syncthreads();
    {
        uint2* dst = fits ? (uint2*)sP : (spill + base);
        for (int i = t; i < cnt; i += 512) {
            unsigned k = bucketed[base + i];
            unsigned lc = k & (BK_COLS - 1);
            unsigned src = k >> BK_SHIFT;
            int q = atomicAdd(&posc[lc], 1);
            uint2 o;
            o.x = src;
            o.y = __float_as_uint(d_e2m[src]);
            dst[q] = o;
        }
    }
    __syncthreads();

    const uint2* P = fits ? (const uint2*)sP : (const uint2*)(spill + base);
    unsigned lane = t & 63;
    unsigned half = lane >> 5;
    unsigned hl = lane & 31;
    int wv = t >> 6;                      // 0..7, 16 cols each
    const unsigned* xw32 = (const unsigned*)xwb;
    int c0 = wv * 16;
    for (int c = c0; c < c0 + 16; ++c) {
        int node = b * BK_COLS + c;
        if (node >= n) break;             // wave-uniform (only last bucket)
        int lo = offs[c], hi = offs[c + 1];
        float accLo = 0.f, accHi = 0.f;
        int i = lo;
        for (; i + 8 <= hi; i += 8) {
            int e0 = i + 4 * (int)half;
            uint2 p0 = P[e0 + 0], p1 = P[e0 + 1], p2 = P[e0 + 2], p3 = P[e0 + 3];
            unsigned u0 = xw32[p0.x * 32u + hl];
            unsigned u1 = xw32[p1.x * 32u + hl];
            unsigned u2 = xw32[p2.x * 32u + hl];
            unsigned u3 = xw32[p3.x * 32u + hl];
            float w0 = __uint_as_float(p0.y), w1 = __uint_as_float(p1.y);
            float w2 = __uint_as_float(p2.y), w3 = __uint_as_float(p3.y);
            accLo += w0 * __uint_as_float(u0 << 16) + w1 * __uint_as_float(u1 << 16)
                   + w2 * __uint_as_float(u2 << 16) + w3 * __uint_as_float(u3 << 16);
            accHi += w0 * __uint_as_float(u0 & 0xFFFF0000u) + w1 * __uint_as_float(u1 & 0xFFFF0000u)
                   + w2 * __uint_as_float(u2 & 0xFFFF0000u) + w3 * __uint_as_float(u3 & 0xFFFF0000u);
        }
        for (; i + 4 <= hi; i += 4) {
            int e0 = i + 2 * (int)half;
            uint2 p0 = P[e0 + 0], p1 = P[e0 + 1];
            unsigned u0 = xw32[p0.x * 32u + hl];
            unsigned u1 = xw32[p1.x * 32u + hl];
            float w0 = __uint_as_float(p0.y), w1 = __uint_as_float(p1.y);
            accLo += w0 * __uint_as_float(u0 << 16) + w1 * __uint_as_float(u1 << 16);
            accHi += w0 * __uint_as_float(u0 & 0xFFFF0000u) + w1 * __uint_as_float(u1 & 0xFFFF0000u);
        }
        {
            int rem = hi - i;
            int j0 = 2 * (int)half;
            int j1 = min(j0 + 2, rem);
            for (int j = j0; j < j1; ++j) {
                uint2 p = P[i + j];
                unsigned u = xw32[p.x * 32u + hl];
                float w = __uint_as_float(p.y);
                accLo += w * __uint_as_float(u << 16);
                accHi += w * __uint_as_float(u & 0xFFFF0000u);
            }
        }
        accLo += __shfl_xor(accLo, 32);
        accHi += __shfl_xor(accHi, 32);

        unsigned us = xw32[(unsigned)node * 32u + hl];
        float xsLo = __uint_as_float(us << 16);
        float xsHi = __uint_as_float(us & 0xFFFF0000u);
        float2 bb = *(const float2*)&bias[2 * hl];
        float gs = gso2[node], dn = d_e3p[node];
        float vLo = gs * xsLo + 2.0f * bb.x + dn * accLo;
        float vHi = gs * xsHi + 2.0f * bb.y + dn * accHi;
        float m = fmaxf(vLo, vHi);
#pragma unroll
        for (int d = 1; d < 32; d <<= 1) m = fmaxf(m, __shfl_xor(m, d));
        float s = expf(vLo - m) + expf(vHi - m);
#pragma unroll
        for (int d = 1; d < 32; d <<= 1) s += __shfl_xor(s, d);
        if (half == 0) {
            float ls = logf(s);
            float2 o;
            o.x = vLo - m - ls;
            o.y = vHi - m - ls;
            *(float2*)&out[(size_t)node * DOUT + 2 * hl] = o;
        }
    }
}

// ---------------------------------------------------------------------------
extern "C" void kernel_launch(void* const* d_in, const int* in_sizes, int n_in,
                              void* d_out, int out_size, void* d_ws, size_t ws_size,
                              hipStream_t stream) {
    const float* x     = (const float*)d_in[0];
    const int*   ei    = (const int*)d_in[1];
    const float* diags = (const float*)d_in[3];
    const float* W     = (const float*)d_in[4];
    const float* b     = (const float*)d_in[5];
    const float* m1    = (const float*)d_in[6];
    const float* m2    = (const float*)d_in[7];
    const float* m3    = (const float*)d_in[8];
    const float* e1    = (const float*)d_in[9];
    const float* e2    = (const float*)d_in[10];
    const float* e3    = (const float*)d_in[11];
    float* out = (float*)d_out;

    const int n = in_sizes[3];            // 100000
    const int e_cnt = in_sizes[1] / 2;    // 1600000
    const int nbk = (n + BK_COLS - 1) >> BK_SHIFT;          // 782 buckets
    const int chunk = (e_cnt + NBLK - 1) / NBLK;            // 25000 edges/chunk

    char* ws = (char*)d_ws;
    // --- small-matrix region (fixed offsets) ---
    float*    Wo   = (float*)ws;                 // 8192 floats = 32KB
    float*    gG   = (float*)(ws + 32768);       // 12 x 4096 floats
    float*    gT   = gG  + 4096;
    float*    gA   = gT  + 4096;
    float*    gAn  = gA  + 4096;
    float*    gA0  = gAn + 4096;
    float*    gP   = gA0 + 4096;
    float*    gPn  = gP  + 4096;
    float*    gB0  = gPn + 4096;
    float*    gB1  = gB0 + 4096;
    float*    gB2  = gB1 + 4096;
    float*    gB3  = gB2 + 4096;
    float*    gB4  = gB3 + 4096;
    float*    gSc  = gB4 + 4096;                 // 2 floats (pad to 64)
    // --- big arrays ---
    float*          d_e2m    = gSc + 64;               // n
    float*          d_e3p    = d_e2m + n;              // n
    float*          gso2     = d_e3p + n;              // n
    unsigned short* xwb      = (unsigned short*)(gso2 + n);   // n*64 bf16
    unsigned*       bucketed = (unsigned*)(xwb + (size_t)n * DOUT); // e_cnt
    unsigned*       blk_hist = bucketed + e_cnt;               // NBLK*1024
    unsigned*       boff     = blk_hist + (size_t)NBLK * NBK_STRIDE; // nbk+8
    uintptr_t pp = ((uintptr_t)(boff + nbk + 8) + 15) & ~(uintptr_t)15;
    uint2*          spill    = (uint2*)pp;                     // e_cnt (fallback only)

    // ---- Bjorck chain: 14 small multi-block dispatches ----------------------
    gram_pass<<<8, 256, 0, stream>>>(W, gG);                              // G
    mm_pass<<<8, 256, 0, stream>>>(gG, nullptr, gG, gT, nullptr, nullptr); // H = G^2
    mm_pass<<<8, 256, 0, stream>>>(gT, nullptr, gT, gA, nullptr, nullptr); // H2 = G^4
    power_prep<<<1, 256, 0, stream>>>(gA, gG, gSc, gA0, gB0);             // sc,rs,A0,B0
    mm_pass<<<8, 256, 0, stream>>>(gA0, nullptr, gB0, gT, nullptr, nullptr); // T = A0@B0
    mm_pass<<<8, 256, 0, stream>>>(gT, nullptr, gB0, gA, nullptr, gB1);   // A1 (+B1)
    mm_pass<<<16, 256, 0, stream>>>(gB0, gA, gB1, gP, gT, nullptr);       // P=B0B1, T=A1B1
    mm_pass<<<8, 256, 0, stream>>>(gT, nullptr, gB1, gAn, nullptr, gB2);  // A2 (+B2)
    mm_pass<<<16, 256, 0, stream>>>(gP, gAn, gB2, gPn, gT, nullptr);      // P=PB2, T=A2B2
    mm_pass<<<8, 256, 0, stream>>>(gT, nullptr, gB2, gA, nullptr, gB3);   // A3 (+B3)
    mm_pass<<<16, 256, 0, stream>>>(gPn, gA, gB3, gP, gT, nullptr);       // P=PB3, T=A3B3
    mm_pass<<<8, 256, 0, stream>>>(gT, nullptr, gB3, gAn, nullptr, gB4);  // A4 (+B4)
    mm_pass<<<8, 256, 0, stream>>>(gP, nullptr, gB4, gPn, nullptr, nullptr); // P final
    wo_pass<<<8, 256, 0, stream>>>(W, gPn, gSc, Wo);                      // Wo

    // ---- node prep + feature transform ------------------------------------
    node_prep<<<(n + 255) / 256, 256, 0, stream>>>(diags, m1, m2, m3, e1, e2, e3,
                                                   d_e2m, d_e3p, gso2, n);
    xw_kernel<<<(n + XN - 1) / XN, 256, 0, stream>>>(x, Wo, xwb, n);
    // ---- bucket binning -----------------------------------------------------
    b1_hist<<<NBLK, 256, 0, stream>>>(ei, blk_hist, e_cnt, chunk, nbk);
    s_scan<<<1, 1024, 0, stream>>>(blk_hist, boff, nbk, e_cnt);
    b2_scatter<<<NBLK, 256, 0, stream>>>(ei, blk_hist, bucketed, e_cnt, chunk, nbk);
    // ---- fused per-bucket CSR sort + gather + softmax -----------------------
    csr_gather<<<nbk, 512, 0, stream>>>(bucketed, boff, d_e2m, d_e3p,
                                        xwb, gso2, b, spill, out, n);
}

// Round 20
// 240.279 us; speedup vs baseline: 3.6906x; 1.0605x over previous
//
#include <hip/hip_runtime.h>
#include <math.h>

#define DIN 128
#define DOUT 64

#define NBLK 64             // binning blocks (write locality: ~32-edge runs)
#define BK_SHIFT 7          // 128 cols per bucket
#define BK_COLS 128
#define NBK_STRIDE 1024     // LDS hist stride
#define REGION 4096         // fixed slots per bucket (max bucket ~2205)
#define CCAP 3072           // LDS staging capacity in csr_gather

__device__ __forceinline__ float safe_pow(float d, float e) {
    float p = powf(d, e);
    return isinf(p) ? 0.0f : p;
}

__device__ __forceinline__ float dot4(float4 a, float4 b) {
    return a.x * b.x + a.y * b.y + a.z * b.z + a.w * b.w;
}

__device__ __forceinline__ unsigned short f32_to_bf16(float f) {
    unsigned bits = __float_as_uint(f);
    unsigned r = (bits + 0x7FFFu + ((bits >> 16) & 1u)) >> 16;
    return (unsigned short)r;
}

// ---------------------------------------------------------------------------
// Plain multi-block 64x64 matmul (8/16 blocks). B SYMMETRIC (rows as cols).
// Optional CB = 1.5I - 0.5*C. Separate ~3µs launches (grid.sync costs ~9µs).
// ---------------------------------------------------------------------------
__global__ __launch_bounds__(256) void mm_pass(const float* A1, const float* A2,
                                               const float* Bsrc,
                                               float* C1, float* C2, float* CB) {
    int t = threadIdx.x;
    bool second = (blockIdx.x >= 8);
    int blk = blockIdx.x & 7;
    const float* As = second ? A2 : A1;
    float* Cs = second ? C2 : C1;
    int c = t & 63;
    int r0 = blk * 8 + (t >> 6) * 2;
    float acc0 = 0.f, acc1 = 0.f;
#pragma unroll
    for (int k4 = 0; k4 < 16; ++k4) {
        float4 b  = *(const float4*)&Bsrc[c * 64 + k4 * 4];
        float4 a0 = *(const float4*)&As[r0 * 64 + k4 * 4];
        float4 a1 = *(const float4*)&As[(r0 + 1) * 64 + k4 * 4];
        acc0 += dot4(a0, b);
        acc1 += dot4(a1, b);
    }
    Cs[r0 * 64 + c] = acc0;
    Cs[(r0 + 1) * 64 + c] = acc1;
    if (CB != nullptr && !second) {
        CB[r0 * 64 + c]       = ((r0 == c)     ? 1.5f : 0.0f) - 0.5f * acc0;
        CB[(r0 + 1) * 64 + c] = ((r0 + 1 == c) ? 1.5f : 0.0f) - 0.5f * acc1;
    }
}

// ---------------------------------------------------------------------------
// G = W @ W^T (64x64, K=128), 8 blocks.
// ---------------------------------------------------------------------------
__global__ __launch_bounds__(256) void gram_pass(const float* W, float* G) {
    int t = threadIdx.x;
    int c = t & 63;
    int r0 = blockIdx.x * 8 + (t >> 6) * 2;
    float acc0 = 0.f, acc1 = 0.f;
#pragma unroll
    for (int k4 = 0; k4 < 32; ++k4) {
        float4 b  = *(const float4*)&W[c * 128 + k4 * 4];
        float4 a0 = *(const float4*)&W[r0 * 128 + k4 * 4];
        float4 a1 = *(const float4*)&W[(r0 + 1) * 128 + k4 * 4];
        acc0 += dot4(a0, b);
        acc1 += dot4(a1, b);
    }
    G[r0 * 64 + c] = acc0;
    G[(r0 + 1) * 64 + c] = acc1;
}

// ---------------------------------------------------------------------------
// power iteration on H2 = G^4 (wave 0) + prep A0 = rs*G, B0 = 1.5I - 0.5*A0.
// ---------------------------------------------------------------------------
__global__ __launch_bounds__(256) void power_prep(const float* gH2, const float* gG,
                                                  float* gSc, float* gA0, float* gB0) {
    __shared__ float sS[2];
    int t = threadIdx.x;
    if (t < 64) {
        float tr = gH2[t * 65];
#pragma unroll
        for (int d = 1; d < 64; d <<= 1) tr += __shfl_xor(tr, d);
        float inv_tr = 1.0f / tr;
        float4 g4[16];
#pragma unroll
        for (int j4 = 0; j4 < 16; ++j4) {
            float4 v = *(const float4*)&gH2[t * 64 + j4 * 4];
            v.x *= inv_tr; v.y *= inv_tr; v.z *= inv_tr; v.w *= inv_tr;
            g4[j4] = v;
        }
        unsigned h = (unsigned)t * 2654435761u;
        float xv = 0.5f + (float)((h >> 17) & 0x7fff) * (1.0f / 32768.0f);
        float yv = 0.f;
        for (int it = 0; it < 8; ++it) {
            float p0 = 0.f, p1 = 0.f, p2 = 0.f, p3 = 0.f;
#pragma unroll
            for (int j4 = 0; j4 < 16; ++j4) {
                float4 xx;
                xx.x = __shfl(xv, j4 * 4 + 0);
                xx.y = __shfl(xv, j4 * 4 + 1);
                xx.z = __shfl(xv, j4 * 4 + 2);
                xx.w = __shfl(xv, j4 * 4 + 3);
                float dd = dot4(g4[j4], xx);
                if (j4 < 4) p0 += dd; else if (j4 < 8) p1 += dd;
                else if (j4 < 12) p2 += dd; else p3 += dd;
            }
            yv = (p0 + p1) + (p2 + p3);
            if (it < 7) xv = yv;
        }
        float num = xv * yv, den = xv * xv;
#pragma unroll
        for (int d = 1; d < 64; d <<= 1) {
            num += __shfl_xor(num, d);
            den += __shfl_xor(den, d);
        }
        if (t == 0) {
            float lam_h2 = tr * num / den;        // = sigma^8
            float sig = powf(lam_h2, 0.125f);
            float sc = 1.0f / (1.1f * sig);
            float rs = 1.0f / (1.21f * sig * sig);
            gSc[0] = sc; gSc[1] = rs;
            sS[0] = sc; sS[1] = rs;
        }
    }
    __syncthreads();
    float rs = sS[1];
    for (int idx = t; idx < 4096; idx += 256) {
        int r = idx >> 6, c2 = idx & 63;
        float a0 = rs * gG[idx];
        gA0[idx] = a0;
        gB0[idx] = ((r == c2) ? 1.5f : 0.0f) - 0.5f * a0;
    }
}

// ---------------------------------------------------------------------------
// Wo = sc * P @ W  (64x128), 8 blocks.
// ---------------------------------------------------------------------------
__global__ __launch_bounds__(256) void wo_pass(const float* W, const float* P,
                                               const float* gSc, float* Wo) {
    int t = threadIdx.x;
    int c = t & 63;
    int r0 = blockIdx.x * 8 + (t >> 6) * 2;
    float a00 = 0.f, a01 = 0.f, a10 = 0.f, a11 = 0.f;
#pragma unroll 4
    for (int j = 0; j < 64; ++j) {
        float p0 = P[r0 * 64 + j];
        float p1 = P[(r0 + 1) * 64 + j];
        float w0 = W[j * 128 + c];
        float w1 = W[j * 128 + c + 64];
        a00 += p0 * w0; a01 += p0 * w1;
        a10 += p1 * w0; a11 += p1 * w1;
    }
    float sc = gSc[0];
    Wo[r0 * 128 + c]            = sc * a00;
    Wo[r0 * 128 + c + 64]       = sc * a01;
    Wo[(r0 + 1) * 128 + c]      = sc * a10;
    Wo[(r0 + 1) * 128 + c + 64] = sc * a11;
}

// ---------------------------------------------------------------------------
// per-node prep; also initializes the per-bucket global cursors
// (gcur[b] = b*REGION) consumed by bin_scatter.
// ---------------------------------------------------------------------------
__global__ void node_prep(const float* __restrict__ diags,
                          const float* m1, const float* m2, const float* m3,
                          const float* e1, const float* e2, const float* e3,
                          float* __restrict__ d_e2m, float* __restrict__ d_e3p,
                          float* __restrict__ gso2,
                          unsigned* __restrict__ gcur, int nbk, int n) {
    int i = blockIdx.x * blockDim.x + threadIdx.x;
    if (i < nbk) gcur[i] = (unsigned)i * REGION;
    if (i >= n) return;
    float d = diags[i];
    float p1 = safe_pow(d, e1[0]);
    float p2 = safe_pow(d, e2[0]);
    float p3 = safe_pow(d, e3[0]);
    float vm2 = m2[0];
    d_e2m[i] = vm2 * p2;
    d_e3p[i] = p3;
    gso2[i] = m1[0] * p1 + vm2 * p2 * p3 + m3[0];
}

// ---------------------------------------------------------------------------
// xw = x @ Wo^T — register-tiled GEMM; OUTPUT IN BF16.
// ---------------------------------------------------------------------------
#define XN 64
#define XS 132
__global__ __launch_bounds__(256) void xw_kernel(const float* __restrict__ x,
                                                 const float* __restrict__ Wo,
                                                 unsigned short* __restrict__ xwb,
                                                 int n) {
    __shared__ __align__(16) float xs[XN * XS];
    __shared__ __align__(16) float ws[DOUT * XS];
    int t = threadIdx.x;
    int base = blockIdx.x * XN;
    for (int f = t; f < DOUT * (DIN / 4); f += 256) {
        int r = f >> 5, c = f & 31;
        *(float4*)&ws[r * XS + c * 4] = *(const float4*)&Wo[r * DIN + c * 4];
    }
    for (int f = t; f < XN * (DIN / 4); f += 256) {
        int r = f >> 5, c = f & 31;
        int node = base + r;
        float4 v = make_float4(0.f, 0.f, 0.f, 0.f);
        if (node < n) v = *(const float4*)&x[(size_t)node * DIN + c * 4];
        *(float4*)&xs[r * XS + c * 4] = v;
    }
    __syncthreads();
    int tn = t >> 4;
    int td = t & 15;
    float acc[4][4] = {};
#pragma unroll 2
    for (int k4 = 0; k4 < DIN / 4; ++k4) {
        float4 a[4], w[4];
#pragma unroll
        for (int r = 0; r < 4; ++r) a[r] = *(const float4*)&xs[(tn * 4 + r) * XS + k4 * 4];
#pragma unroll
        for (int c = 0; c < 4; ++c) w[c] = *(const float4*)&ws[(td + c * 16) * XS + k4 * 4];
#pragma unroll
        for (int r = 0; r < 4; ++r)
#pragma unroll
            for (int c = 0; c < 4; ++c) acc[r][c] += dot4(a[r], w[c]);
    }
#pragma unroll
    for (int r = 0; r < 4; ++r) {
        int node = base + tn * 4 + r;
        if (node >= n) break;
#pragma unroll
        for (int c = 0; c < 4; ++c)
            xwb[(size_t)node * DOUT + td + c * 16] = f32_to_bf16(acc[r][c]);
    }
}

// ---------------------------------------------------------------------------
// FUSED binning (replaces b1_hist + s_scan + b2_scatter):
// pass 1: LDS histogram of this block's 25K-edge chunk;
// reserve: ONE global atomicAdd per (block,bucket) -> contiguous run
//          (keeps the proven ~32-edge write locality);
// pass 2: scatter packed (src<<7 | lcol) into the reserved run.
// Bucket b owns fixed region [b*REGION, b*REGION + cnt); cnt via gcur.
// ---------------------------------------------------------------------------
__global__ __launch_bounds__(256) void bin_scatter(const int* __restrict__ ei,
                                                   unsigned* __restrict__ gcur,
                                                   unsigned* __restrict__ bucketed,
                                                   int e_cnt, int chunk, int nbk) {
    __shared__ int h[NBK_STRIDE];
    int b = blockIdx.x, t = threadIdx.x;
    for (int j = t; j < NBK_STRIDE; j += 256) h[j] = 0;
    __syncthreads();
    int lo = b * chunk, hi = min(lo + chunk, e_cnt);
    for (int e = lo + t; e < hi; e += 256)
        atomicAdd(&h[ei[e_cnt + e] >> BK_SHIFT], 1);
    __syncthreads();
    for (int j = t; j < nbk; j += 256) {
        int c = h[j];
        h[j] = (c > 0) ? (int)atomicAdd(&gcur[j], (unsigned)c) : 0;
    }
    __syncthreads();
    for (int e = lo + t; e < hi; e += 256) {
        int col = ei[e_cnt + e];
        int src = ei[e];
        int pos = atomicAdd(&h[col >> BK_SHIFT], 1);
        bucketed[pos] = ((unsigned)src << BK_SHIFT) | (unsigned)(col & (BK_COLS - 1));
    }
}

// ---------------------------------------------------------------------------
// FUSED per-bucket CSR sort + gather + self-loop + bias + log-softmax.
// One 512-thread block per bucket; bucket region [b*REGION, b*REGION+cnt),
// cnt = gcur[b] - b*REGION. Counting-sort into LDS, then 8 waves gather
// 16 nodes each with the dword-packed scheme.
// ---------------------------------------------------------------------------
__global__ __launch_bounds__(512) void csr_gather(const unsigned* __restrict__ bucketed,
                                                  const unsigned* __restrict__ gcur,
                                                  const float* __restrict__ d_e2m,
                                                  const float* __restrict__ d_e3p,
                                                  const unsigned short* __restrict__ xwb,
                                                  const float* __restrict__ gso2,
                                                  const float* __restrict__ bias,
                                                  uint2* __restrict__ spill,
                                                  float* __restrict__ out, int n) {
    __shared__ __align__(16) uint2 sP[CCAP];
    __shared__ int shc[BK_COLS], scc[BK_COLS], posc[BK_COLS];
    __shared__ int offs[BK_COLS + 1];
    int b = blockIdx.x, t = threadIdx.x;
    int base = b * REGION;
    int cnt = (int)gcur[b] - base;
    bool fits = (cnt <= CCAP);

    if (t < BK_COLS) shc[t] = 0;
    __syncthreads();
    for (int i = t; i < cnt; i += 512)
        atomicAdd(&shc[bucketed[base + i] & (BK_COLS - 1)], 1);
    __syncthreads();
    if (t < BK_COLS) scc[t] = shc[t];
    __syncthreads();
    for (int d = 1; d < BK_COLS; d <<= 1) {
        int u = 0;
        if (t < BK_COLS && t >= d) u = scc[t - d];
        __syncthreads();
        if (t < BK_COLS) scc[t] += u;
        __syncthreads();
    }
    if (t < BK_COLS) {
        int pre = scc[t] - shc[t];
        posc[t] = pre;
        offs[t] = pre;
    }
    if (t == 0) offs[BK_COLS] = cnt;
    __syncthreads();
    {
        uint2* dst = fits ? (uint2*)sP : (spill + base);
        for (int i = t; i < cnt; i += 512) {
            unsigned k = bucketed[base + i];
            unsigned lc = k & (BK_COLS - 1);
            unsigned src = k >> BK_SHIFT;
            int q = atomicAdd(&posc[lc], 1);
            uint2 o;
            o.x = src;
            o.y = __float_as_uint(d_e2m[src]);
            dst[q] = o;
        }
    }
    __syncthreads();

    const uint2* P = fits ? (const uint2*)sP : (const uint2*)(spill + base);
    unsigned lane = t & 63;
    unsigned half = lane >> 5;
    unsigned hl = lane & 31;
    int wv = t >> 6;                      // 0..7, 16 cols each
    const unsigned* xw32 = (const unsigned*)xwb;
    int c0 = wv * 16;
    for (int c = c0; c < c0 + 16; ++c) {
        int node = b * BK_COLS + c;
        if (node >= n) break;             // wave-uniform (only last bucket)
        int lo = offs[c], hi = offs[c + 1];
        float accLo = 0.f, accHi = 0.f;
        int i = lo;
        for (; i + 8 <= hi; i += 8) {
            int e0 = i + 4 * (int)half;
            uint2 p0 = P[e0 + 0], p1 = P[e0 + 1], p2 = P[e0 + 2], p3 = P[e0 + 3];
            unsigned u0 = xw32[p0.x * 32u + hl];
            unsigned u1 = xw32[p1.x * 32u + hl];
            unsigned u2 = xw32[p2.x * 32u + hl];
            unsigned u3 = xw32[p3.x * 32u + hl];
            float w0 = __uint_as_float(p0.y), w1 = __uint_as_float(p1.y);
            float w2 = __uint_as_float(p2.y), w3 = __uint_as_float(p3.y);
            accLo += w0 * __uint_as_float(u0 << 16) + w1 * __uint_as_float(u1 << 16)
                   + w2 * __uint_as_float(u2 << 16) + w3 * __uint_as_float(u3 << 16);
            accHi += w0 * __uint_as_float(u0 & 0xFFFF0000u) + w1 * __uint_as_float(u1 & 0xFFFF0000u)
                   + w2 * __uint_as_float(u2 & 0xFFFF0000u) + w3 * __uint_as_float(u3 & 0xFFFF0000u);
        }
        for (; i + 4 <= hi; i += 4) {
            int e0 = i + 2 * (int)half;
            uint2 p0 = P[e0 + 0], p1 = P[e0 + 1];
            unsigned u0 = xw32[p0.x * 32u + hl];
            unsigned u1 = xw32[p1.x * 32u + hl];
            float w0 = __uint_as_float(p0.y), w1 = __uint_as_float(p1.y);
            accLo += w0 * __uint_as_float(u0 << 16) + w1 * __uint_as_float(u1 << 16);
            accHi += w0 * __uint_as_float(u0 & 0xFFFF0000u) + w1 * __uint_as_float(u1 & 0xFFFF0000u);
        }
        {
            int rem = hi - i;
            int j0 = 2 * (int)half;
            int j1 = min(j0 + 2, rem);
            for (int j = j0; j < j1; ++j) {
                uint2 p = P[i + j];
                unsigned u = xw32[p.x * 32u + hl];
                float w = __uint_as_float(p.y);
                accLo += w * __uint_as_float(u << 16);
                accHi += w * __uint_as_float(u & 0xFFFF0000u);
            }
        }
        accLo += __shfl_xor(accLo, 32);
        accHi += __shfl_xor(accHi, 32);

        unsigned us = xw32[(unsigned)node * 32u + hl];
        float xsLo = __uint_as_float(us << 16);
        float xsHi = __uint_as_float(us & 0xFFFF0000u);
        float2 bb = *(const float2*)&bias[2 * hl];
        float gs = gso2[node], dn = d_e3p[node];
        float vLo = gs * xsLo + 2.0f * bb.x + dn * accLo;
        float vHi = gs * xsHi + 2.0f * bb.y + dn * accHi;
        float m = fmaxf(vLo, vHi);
#pragma unroll
        for (int d = 1; d < 32; d <<= 1) m = fmaxf(m, __shfl_xor(m, d));
        float s = expf(vLo - m) + expf(vHi - m);
#pragma unroll
        for (int d = 1; d < 32; d <<= 1) s += __shfl_xor(s, d);
        if (half == 0) {
            float ls = logf(s);
            float2 o;
            o.x = vLo - m - ls;
            o.y = vHi - m - ls;
            *(float2*)&out[(size_t)node * DOUT + 2 * hl] = o;
        }
    }
}

// ---------------------------------------------------------------------------
extern "C" void kernel_launch(void* const* d_in, const int* in_sizes, int n_in,
                              void* d_out, int out_size, void* d_ws, size_t ws_size,
                              hipStream_t stream) {
    const float* x     = (const float*)d_in[0];
    const int*   ei    = (const int*)d_in[1];
    const float* diags = (const float*)d_in[3];
    const float* W     = (const float*)d_in[4];
    const float* b     = (const float*)d_in[5];
    const float* m1    = (const float*)d_in[6];
    const float* m2    = (const float*)d_in[7];
    const float* m3    = (const float*)d_in[8];
    const float* e1    = (const float*)d_in[9];
    const float* e2    = (const float*)d_in[10];
    const float* e3    = (const float*)d_in[11];
    float* out = (float*)d_out;

    const int n = in_sizes[3];            // 100000
    const int e_cnt = in_sizes[1] / 2;    // 1600000
    const int nbk = (n + BK_COLS - 1) >> BK_SHIFT;          // 782 buckets
    const int chunk = (e_cnt + NBLK - 1) / NBLK;            // 25000 edges/chunk

    char* ws = (char*)d_ws;
    // --- small-matrix region (fixed offsets) ---
    float*    Wo   = (float*)ws;                 // 8192 floats = 32KB
    float*    gG   = (float*)(ws + 32768);       // 12 x 4096 floats
    float*    gT   = gG  + 4096;
    float*    gA   = gT  + 4096;
    float*    gAn  = gA  + 4096;
    float*    gA0  = gAn + 4096;
    float*    gP   = gA0 + 4096;
    float*    gPn  = gP  + 4096;
    float*    gB0  = gPn + 4096;
    float*    gB1  = gB0 + 4096;
    float*    gB2  = gB1 + 4096;
    float*    gB3  = gB2 + 4096;
    float*    gB4  = gB3 + 4096;
    float*    gSc  = gB4 + 4096;                 // 2 floats (pad to 64)
    // --- big arrays ---
    float*          d_e2m    = gSc + 64;               // n
    float*          d_e3p    = d_e2m + n;              // n
    float*          gso2     = d_e3p + n;              // n
    unsigned short* xwb      = (unsigned short*)(gso2 + n);       // n*64 bf16
    unsigned*       gcur     = (unsigned*)(xwb + (size_t)n * DOUT); // nbk+8
    uintptr_t bb_ = ((uintptr_t)(gcur + nbk + 8) + 15) & ~(uintptr_t)15;
    unsigned*       bucketed = (unsigned*)bb_;                     // nbk*REGION u32
    uint2*          spill    = (uint2*)(bucketed + (size_t)nbk * REGION); // nbk*REGION u2

    // ---- Bjorck chain: 14 small multi-block dispatches ----------------------
    gram_pass<<<8, 256, 0, stream>>>(W, gG);                              // G
    mm_pass<<<8, 256, 0, stream>>>(gG, nullptr, gG, gT, nullptr, nullptr); // H = G^2
    mm_pass<<<8, 256, 0, stream>>>(gT, nullptr, gT, gA, nullptr, nullptr); // H2 = G^4
    power_prep<<<1, 256, 0, stream>>>(gA, gG, gSc, gA0, gB0);             // sc,rs,A0,B0
    mm_pass<<<8, 256, 0, stream>>>(gA0, nullptr, gB0, gT, nullptr, nullptr); // T = A0@B0
    mm_pass<<<8, 256, 0, stream>>>(gT, nullptr, gB0, gA, nullptr, gB1);   // A1 (+B1)
    mm_pass<<<16, 256, 0, stream>>>(gB0, gA, gB1, gP, gT, nullptr);       // P=B0B1, T=A1B1
    mm_pass<<<8, 256, 0, stream>>>(gT, nullptr, gB1, gAn, nullptr, gB2);  // A2 (+B2)
    mm_pass<<<16, 256, 0, stream>>>(gP, gAn, gB2, gPn, gT, nullptr);      // P=PB2, T=A2B2
    mm_pass<<<8, 256, 0, stream>>>(gT, nullptr, gB2, gA, nullptr, gB3);   // A3 (+B3)
    mm_pass<<<16, 256, 0, stream>>>(gPn, gA, gB3, gP, gT, nullptr);       // P=PB3, T=A3B3
    mm_pass<<<8, 256, 0, stream>>>(gT, nullptr, gB3, gAn, nullptr, gB4);  // A4 (+B4)
    mm_pass<<<8, 256, 0, stream>>>(gP, nullptr, gB4, gPn, nullptr, nullptr); // P final
    wo_pass<<<8, 256, 0, stream>>>(W, gPn, gSc, Wo);                      // Wo

    // ---- node prep (+ gcur init) + feature transform -----------------------
    node_prep<<<(n + 255) / 256, 256, 0, stream>>>(diags, m1, m2, m3, e1, e2, e3,
                                                   d_e2m, d_e3p, gso2, gcur, nbk, n);
    xw_kernel<<<(n + XN - 1) / XN, 256, 0, stream>>>(x, Wo, xwb, n);
    // ---- fused binning ------------------------------------------------------
    bin_scatter<<<NBLK, 256, 0, stream>>>(ei, gcur, bucketed, e_cnt, chunk, nbk);
    // ---- fused per-bucket CSR sort + gather + softmax -----------------------
    csr_gather<<<nbk, 512, 0, stream>>>(bucketed, gcur, d_e2m, d_e3p,
                                        xwb, gso2, b, spill, out, n);
}

// Round 21
// 208.971 us; speedup vs baseline: 4.2436x; 1.1498x over previous
//
#include <hip/hip_runtime.h>
#include <math.h>

#define DIN 128
#define DOUT 64

#define NBLK 64             // binning blocks (write locality: ~32-edge runs)
#define BK_SHIFT 7          // 128 cols per bucket
#define BK_COLS 128
#define NBK_STRIDE 1024     // LDS hist stride
#define REGION 4096         // fixed slots per bucket (max bucket ~2205)
#define CCAP 3072           // LDS staging capacity in csr_gather

__device__ __forceinline__ float safe_pow(float d, float e) {
    float p = powf(d, e);
    return isinf(p) ? 0.0f : p;
}

__device__ __forceinline__ float dot4(float4 a, float4 b) {
    return a.x * b.x + a.y * b.y + a.z * b.z + a.w * b.w;
}

__device__ __forceinline__ unsigned short f32_to_bf16(float f) {
    unsigned bits = __float_as_uint(f);
    unsigned r = (bits + 0x7FFFu + ((bits >> 16) & 1u)) >> 16;
    return (unsigned short)r;
}

// ---------------------------------------------------------------------------
// Plain multi-block 64x64 matmul (8/16 blocks). B SYMMETRIC (rows as cols).
// Optional CB = 1.5I - 0.5*C. Separate ~3µs launches (grid.sync costs ~9µs).
// ---------------------------------------------------------------------------
__global__ __launch_bounds__(256) void mm_pass(const float* A1, const float* A2,
                                               const float* Bsrc,
                                               float* C1, float* C2, float* CB) {
    int t = threadIdx.x;
    bool second = (blockIdx.x >= 8);
    int blk = blockIdx.x & 7;
    const float* As = second ? A2 : A1;
    float* Cs = second ? C2 : C1;
    int c = t & 63;
    int r0 = blk * 8 + (t >> 6) * 2;
    float acc0 = 0.f, acc1 = 0.f;
#pragma unroll
    for (int k4 = 0; k4 < 16; ++k4) {
        float4 b  = *(const float4*)&Bsrc[c * 64 + k4 * 4];
        float4 a0 = *(const float4*)&As[r0 * 64 + k4 * 4];
        float4 a1 = *(const float4*)&As[(r0 + 1) * 64 + k4 * 4];
        acc0 += dot4(a0, b);
        acc1 += dot4(a1, b);
    }
    Cs[r0 * 64 + c] = acc0;
    Cs[(r0 + 1) * 64 + c] = acc1;
    if (CB != nullptr && !second) {
        CB[r0 * 64 + c]       = ((r0 == c)     ? 1.5f : 0.0f) - 0.5f * acc0;
        CB[(r0 + 1) * 64 + c] = ((r0 + 1 == c) ? 1.5f : 0.0f) - 0.5f * acc1;
    }
}

// ---------------------------------------------------------------------------
// G = W @ W^T (64x64, K=128), 8 blocks.
// ---------------------------------------------------------------------------
__global__ __launch_bounds__(256) void gram_pass(const float* W, float* G) {
    int t = threadIdx.x;
    int c = t & 63;
    int r0 = blockIdx.x * 8 + (t >> 6) * 2;
    float acc0 = 0.f, acc1 = 0.f;
#pragma unroll
    for (int k4 = 0; k4 < 32; ++k4) {
        float4 b  = *(const float4*)&W[c * 128 + k4 * 4];
        float4 a0 = *(const float4*)&W[r0 * 128 + k4 * 4];
        float4 a1 = *(const float4*)&W[(r0 + 1) * 128 + k4 * 4];
        acc0 += dot4(a0, b);
        acc1 += dot4(a1, b);
    }
    G[r0 * 64 + c] = acc0;
    G[(r0 + 1) * 64 + c] = acc1;
}

// ---------------------------------------------------------------------------
// power iteration on H2 = G^4 (wave 0) + prep A0 = rs*G, B0 = 1.5I - 0.5*A0.
// ---------------------------------------------------------------------------
__global__ __launch_bounds__(256) void power_prep(const float* gH2, const float* gG,
                                                  float* gSc, float* gA0, float* gB0) {
    __shared__ float sS[2];
    int t = threadIdx.x;
    if (t < 64) {
        float tr = gH2[t * 65];
#pragma unroll
        for (int d = 1; d < 64; d <<= 1) tr += __shfl_xor(tr, d);
        float inv_tr = 1.0f / tr;
        float4 g4[16];
#pragma unroll
        for (int j4 = 0; j4 < 16; ++j4) {
            float4 v = *(const float4*)&gH2[t * 64 + j4 * 4];
            v.x *= inv_tr; v.y *= inv_tr; v.z *= inv_tr; v.w *= inv_tr;
            g4[j4] = v;
        }
        unsigned h = (unsigned)t * 2654435761u;
        float xv = 0.5f + (float)((h >> 17) & 0x7fff) * (1.0f / 32768.0f);
        float yv = 0.f;
        for (int it = 0; it < 8; ++it) {
            float p0 = 0.f, p1 = 0.f, p2 = 0.f, p3 = 0.f;
#pragma unroll
            for (int j4 = 0; j4 < 16; ++j4) {
                float4 xx;
                xx.x = __shfl(xv, j4 * 4 + 0);
                xx.y = __shfl(xv, j4 * 4 + 1);
                xx.z = __shfl(xv, j4 * 4 + 2);
                xx.w = __shfl(xv, j4 * 4 + 3);
                float dd = dot4(g4[j4], xx);
                if (j4 < 4) p0 += dd; else if (j4 < 8) p1 += dd;
                else if (j4 < 12) p2 += dd; else p3 += dd;
            }
            yv = (p0 + p1) + (p2 + p3);
            if (it < 7) xv = yv;
        }
        float num = xv * yv, den = xv * xv;
#pragma unroll
        for (int d = 1; d < 64; d <<= 1) {
            num += __shfl_xor(num, d);
            den += __shfl_xor(den, d);
        }
        if (t == 0) {
            float lam_h2 = tr * num / den;        // = sigma^8
            float sig = powf(lam_h2, 0.125f);
            float sc = 1.0f / (1.1f * sig);
            float rs = 1.0f / (1.21f * sig * sig);
            gSc[0] = sc; gSc[1] = rs;
            sS[0] = sc; sS[1] = rs;
        }
    }
    __syncthreads();
    float rs = sS[1];
    for (int idx = t; idx < 4096; idx += 256) {
        int r = idx >> 6, c2 = idx & 63;
        float a0 = rs * gG[idx];
        gA0[idx] = a0;
        gB0[idx] = ((r == c2) ? 1.5f : 0.0f) - 0.5f * a0;
    }
}

// ---------------------------------------------------------------------------
// Wo = sc * P @ W  (64x128), 8 blocks.
// ---------------------------------------------------------------------------
__global__ __launch_bounds__(256) void wo_pass(const float* W, const float* P,
                                               const float* gSc, float* Wo) {
    int t = threadIdx.x;
    int c = t & 63;
    int r0 = blockIdx.x * 8 + (t >> 6) * 2;
    float a00 = 0.f, a01 = 0.f, a10 = 0.f, a11 = 0.f;
#pragma unroll 4
    for (int j = 0; j < 64; ++j) {
        float p0 = P[r0 * 64 + j];
        float p1 = P[(r0 + 1) * 64 + j];
        float w0 = W[j * 128 + c];
        float w1 = W[j * 128 + c + 64];
        a00 += p0 * w0; a01 += p0 * w1;
        a10 += p1 * w0; a11 += p1 * w1;
    }
    float sc = gSc[0];
    Wo[r0 * 128 + c]            = sc * a00;
    Wo[r0 * 128 + c + 64]       = sc * a01;
    Wo[(r0 + 1) * 128 + c]      = sc * a10;
    Wo[(r0 + 1) * 128 + c + 64] = sc * a11;
}

// ---------------------------------------------------------------------------
// per-node prep; also initializes the per-bucket global cursors.
// ---------------------------------------------------------------------------
__global__ void node_prep(const float* __restrict__ diags,
                          const float* m1, const float* m2, const float* m3,
                          const float* e1, const float* e2, const float* e3,
                          float* __restrict__ d_e2m, float* __restrict__ d_e3p,
                          float* __restrict__ gso2,
                          unsigned* __restrict__ gcur, int nbk, int n) {
    int i = blockIdx.x * blockDim.x + threadIdx.x;
    if (i < nbk) gcur[i] = (unsigned)i * REGION;
    if (i >= n) return;
    float d = diags[i];
    float p1 = safe_pow(d, e1[0]);
    float p2 = safe_pow(d, e2[0]);
    float p3 = safe_pow(d, e3[0]);
    float vm2 = m2[0];
    d_e2m[i] = vm2 * p2;
    d_e3p[i] = p3;
    gso2[i] = m1[0] * p1 + vm2 * p2 * p3 + m3[0];
}

// ---------------------------------------------------------------------------
// xw = x @ Wo^T — register-tiled GEMM; OUTPUT IN BF16.
// ---------------------------------------------------------------------------
#define XN 64
#define XS 132
__global__ __launch_bounds__(256) void xw_kernel(const float* __restrict__ x,
                                                 const float* __restrict__ Wo,
                                                 unsigned short* __restrict__ xwb,
                                                 int n) {
    __shared__ __align__(16) float xs[XN * XS];
    __shared__ __align__(16) float ws[DOUT * XS];
    int t = threadIdx.x;
    int base = blockIdx.x * XN;
    for (int f = t; f < DOUT * (DIN / 4); f += 256) {
        int r = f >> 5, c = f & 31;
        *(float4*)&ws[r * XS + c * 4] = *(const float4*)&Wo[r * DIN + c * 4];
    }
    for (int f = t; f < XN * (DIN / 4); f += 256) {
        int r = f >> 5, c = f & 31;
        int node = base + r;
        float4 v = make_float4(0.f, 0.f, 0.f, 0.f);
        if (node < n) v = *(const float4*)&x[(size_t)node * DIN + c * 4];
        *(float4*)&xs[r * XS + c * 4] = v;
    }
    __syncthreads();
    int tn = t >> 4;
    int td = t & 15;
    float acc[4][4] = {};
#pragma unroll 2
    for (int k4 = 0; k4 < DIN / 4; ++k4) {
        float4 a[4], w[4];
#pragma unroll
        for (int r = 0; r < 4; ++r) a[r] = *(const float4*)&xs[(tn * 4 + r) * XS + k4 * 4];
#pragma unroll
        for (int c = 0; c < 4; ++c) w[c] = *(const float4*)&ws[(td + c * 16) * XS + k4 * 4];
#pragma unroll
        for (int r = 0; r < 4; ++r)
#pragma unroll
            for (int c = 0; c < 4; ++c) acc[r][c] += dot4(a[r], w[c]);
    }
#pragma unroll
    for (int r = 0; r < 4; ++r) {
        int node = base + tn * 4 + r;
        if (node >= n) break;
#pragma unroll
        for (int c = 0; c < 4; ++c)
            xwb[(size_t)node * DOUT + td + c * 16] = f32_to_bf16(acc[r][c]);
    }
}

// ---------------------------------------------------------------------------
// FUSED binning. ROUND-20 LESSON: at 256 threads this was latency-bound
// (90µs, VALUBusy 0.6%, occupancy 2.3% — 1 scalar load + 1 LDS atomic per
// serial iteration). Fix: 1024 threads/block (4x waves) + int4 vectorization
// (4 edges per thread-iteration: one 16B coalesced load, 4 independent LDS
// atomics). Chunk geometry (NBLK=64, ~32-edge runs) unchanged — preserves
// the proven write locality.
// ---------------------------------------------------------------------------
__global__ __launch_bounds__(1024) void bin_scatter(const int* __restrict__ ei,
                                                    unsigned* __restrict__ gcur,
                                                    unsigned* __restrict__ bucketed,
                                                    int e_cnt, int chunk, int nbk) {
    __shared__ int h[NBK_STRIDE];
    int b = blockIdx.x, t = threadIdx.x;
    for (int j = t; j < NBK_STRIDE; j += 1024) h[j] = 0;
    __syncthreads();
    int lo = b * chunk, hi = min(lo + chunk, e_cnt);
    const int* cols = ei + e_cnt;
    int nfull = (hi - lo) >> 2;
    // pass 1: histogram (int4)
    for (int g = t; g < nfull; g += 1024) {
        int4 c4 = *(const int4*)&cols[lo + 4 * g];
        atomicAdd(&h[c4.x >> BK_SHIFT], 1);
        atomicAdd(&h[c4.y >> BK_SHIFT], 1);
        atomicAdd(&h[c4.z >> BK_SHIFT], 1);
        atomicAdd(&h[c4.w >> BK_SHIFT], 1);
    }
    {
        int tb = lo + (nfull << 2);
        if (tb + t < hi) atomicAdd(&h[cols[tb + t] >> BK_SHIFT], 1);
    }
    __syncthreads();
    // reserve contiguous runs: one global atomic per (block,bucket)
    for (int j = t; j < nbk; j += 1024) {
        int c = h[j];
        h[j] = (c > 0) ? (int)atomicAdd(&gcur[j], (unsigned)c) : 0;
    }
    __syncthreads();
    // pass 2: scatter packed keys (int4 src+col)
    for (int g = t; g < nfull; g += 1024) {
        int4 c4 = *(const int4*)&cols[lo + 4 * g];
        int4 s4 = *(const int4*)&ei[lo + 4 * g];
        int p0 = atomicAdd(&h[c4.x >> BK_SHIFT], 1);
        bucketed[p0] = ((unsigned)s4.x << BK_SHIFT) | (unsigned)(c4.x & (BK_COLS - 1));
        int p1 = atomicAdd(&h[c4.y >> BK_SHIFT], 1);
        bucketed[p1] = ((unsigned)s4.y << BK_SHIFT) | (unsigned)(c4.y & (BK_COLS - 1));
        int p2 = atomicAdd(&h[c4.z >> BK_SHIFT], 1);
        bucketed[p2] = ((unsigned)s4.z << BK_SHIFT) | (unsigned)(c4.z & (BK_COLS - 1));
        int p3 = atomicAdd(&h[c4.w >> BK_SHIFT], 1);
        bucketed[p3] = ((unsigned)s4.w << BK_SHIFT) | (unsigned)(c4.w & (BK_COLS - 1));
    }
    {
        int tb = lo + (nfull << 2);
        if (tb + t < hi) {
            int col = cols[tb + t];
            int src = ei[tb + t];
            int pos = atomicAdd(&h[col >> BK_SHIFT], 1);
            bucketed[pos] = ((unsigned)src << BK_SHIFT) | (unsigned)(col & (BK_COLS - 1));
        }
    }
}

// ---------------------------------------------------------------------------
// FUSED per-bucket CSR sort + gather + self-loop + bias + log-softmax.
// ---------------------------------------------------------------------------
__global__ __launch_bounds__(512) void csr_gather(const unsigned* __restrict__ bucketed,
                                                  const unsigned* __restrict__ gcur,
                                                  const float* __restrict__ d_e2m,
                                                  const float* __restrict__ d_e3p,
                                                  const unsigned short* __restrict__ xwb,
                                                  const float* __restrict__ gso2,
                                                  const float* __restrict__ bias,
                                                  uint2* __restrict__ spill,
                                                  float* __restrict__ out, int n) {
    __shared__ __align__(16) uint2 sP[CCAP];
    __shared__ int shc[BK_COLS], scc[BK_COLS], posc[BK_COLS];
    __shared__ int offs[BK_COLS + 1];
    int b = blockIdx.x, t = threadIdx.x;
    int base = b * REGION;
    int cnt = (int)gcur[b] - base;
    bool fits = (cnt <= CCAP);

    if (t < BK_COLS) shc[t] = 0;
    __syncthreads();
    for (int i = t; i < cnt; i += 512)
        atomicAdd(&shc[bucketed[base + i] & (BK_COLS - 1)], 1);
    __syncthreads();
    if (t < BK_COLS) scc[t] = shc[t];
    __syncthreads();
    for (int d = 1; d < BK_COLS; d <<= 1) {
        int u = 0;
        if (t < BK_COLS && t >= d) u = scc[t - d];
        __syncthreads();
        if (t < BK_COLS) scc[t] += u;
        __syncthreads();
    }
    if (t < BK_COLS) {
        int pre = scc[t] - shc[t];
        posc[t] = pre;
        offs[t] = pre;
    }
    if (t == 0) offs[BK_COLS] = cnt;
    __syncthreads();
    {
        uint2* dst = fits ? (uint2*)sP : (spill + base);
        for (int i = t; i < cnt; i += 512) {
            unsigned k = bucketed[base + i];
            unsigned lc = k & (BK_COLS - 1);
            unsigned src = k >> BK_SHIFT;
            int q = atomicAdd(&posc[lc], 1);
            uint2 o;
            o.x = src;
            o.y = __float_as_uint(d_e2m[src]);
            dst[q] = o;
        }
    }
    __syncthreads();

    const uint2* P = fits ? (const uint2*)sP : (const uint2*)(spill + base);
    unsigned lane = t & 63;
    unsigned half = lane >> 5;
    unsigned hl = lane & 31;
    int wv = t >> 6;                      // 0..7, 16 cols each
    const unsigned* xw32 = (const unsigned*)xwb;
    int c0 = wv * 16;
    for (int c = c0; c < c0 + 16; ++c) {
        int node = b * BK_COLS + c;
        if (node >= n) break;             // wave-uniform (only last bucket)
        int lo = offs[c], hi = offs[c + 1];
        float accLo = 0.f, accHi = 0.f;
        int i = lo;
        for (; i + 8 <= hi; i += 8) {
            int e0 = i + 4 * (int)half;
            uint2 p0 = P[e0 + 0], p1 = P[e0 + 1], p2 = P[e0 + 2], p3 = P[e0 + 3];
            unsigned u0 = xw32[p0.x * 32u + hl];
            unsigned u1 = xw32[p1.x * 32u + hl];
            unsigned u2 = xw32[p2.x * 32u + hl];
            unsigned u3 = xw32[p3.x * 32u + hl];
            float w0 = __uint_as_float(p0.y), w1 = __uint_as_float(p1.y);
            float w2 = __uint_as_float(p2.y), w3 = __uint_as_float(p3.y);
            accLo += w0 * __uint_as_float(u0 << 16) + w1 * __uint_as_float(u1 << 16)
                   + w2 * __uint_as_float(u2 << 16) + w3 * __uint_as_float(u3 << 16);
            accHi += w0 * __uint_as_float(u0 & 0xFFFF0000u) + w1 * __uint_as_float(u1 & 0xFFFF0000u)
                   + w2 * __uint_as_float(u2 & 0xFFFF0000u) + w3 * __uint_as_float(u3 & 0xFFFF0000u);
        }
        for (; i + 4 <= hi; i += 4) {
            int e0 = i + 2 * (int)half;
            uint2 p0 = P[e0 + 0], p1 = P[e0 + 1];
            unsigned u0 = xw32[p0.x * 32u + hl];
            unsigned u1 = xw32[p1.x * 32u + hl];
            float w0 = __uint_as_float(p0.y), w1 = __uint_as_float(p1.y);
            accLo += w0 * __uint_as_float(u0 << 16) + w1 * __uint_as_float(u1 << 16);
            accHi += w0 * __uint_as_float(u0 & 0xFFFF0000u) + w1 * __uint_as_float(u1 & 0xFFFF0000u);
        }
        {
            int rem = hi - i;
            int j0 = 2 * (int)half;
            int j1 = min(j0 + 2, rem);
            for (int j = j0; j < j1; ++j) {
                uint2 p = P[i + j];
                unsigned u = xw32[p.x * 32u + hl];
                float w = __uint_as_float(p.y);
                accLo += w * __uint_as_float(u << 16);
                accHi += w * __uint_as_float(u & 0xFFFF0000u);
            }
        }
        accLo += __shfl_xor(accLo, 32);
        accHi += __shfl_xor(accHi, 32);

        unsigned us = xw32[(unsigned)node * 32u + hl];
        float xsLo = __uint_as_float(us << 16);
        float xsHi = __uint_as_float(us & 0xFFFF0000u);
        float2 bb = *(const float2*)&bias[2 * hl];
        float gs = gso2[node], dn = d_e3p[node];
        float vLo = gs * xsLo + 2.0f * bb.x + dn * accLo;
        float vHi = gs * xsHi + 2.0f * bb.y + dn * accHi;
        float m = fmaxf(vLo, vHi);
#pragma unroll
        for (int d = 1; d < 32; d <<= 1) m = fmaxf(m, __shfl_xor(m, d));
        float s = expf(vLo - m) + expf(vHi - m);
#pragma unroll
        for (int d = 1; d < 32; d <<= 1) s += __shfl_xor(s, d);
        if (half == 0) {
            float ls = logf(s);
            float2 o;
            o.x = vLo - m - ls;
            o.y = vHi - m - ls;
            *(float2*)&out[(size_t)node * DOUT + 2 * hl] = o;
        }
    }
}

// ---------------------------------------------------------------------------
extern "C" void kernel_launch(void* const* d_in, const int* in_sizes, int n_in,
                              void* d_out, int out_size, void* d_ws, size_t ws_size,
                              hipStream_t stream) {
    const float* x     = (const float*)d_in[0];
    const int*   ei    = (const int*)d_in[1];
    const float* diags = (const float*)d_in[3];
    const float* W     = (const float*)d_in[4];
    const float* b     = (const float*)d_in[5];
    const float* m1    = (const float*)d_in[6];
    const float* m2    = (const float*)d_in[7];
    const float* m3    = (const float*)d_in[8];
    const float* e1    = (const float*)d_in[9];
    const float* e2    = (const float*)d_in[10];
    const float* e3    = (const float*)d_in[11];
    float* out = (float*)d_out;

    const int n = in_sizes[3];            // 100000
    const int e_cnt = in_sizes[1] / 2;    // 1600000
    const int nbk = (n + BK_COLS - 1) >> BK_SHIFT;          // 782 buckets
    const int chunk = (e_cnt + NBLK - 1) / NBLK;            // 25000 edges/chunk

    char* ws = (char*)d_ws;
    // --- small-matrix region (fixed offsets) ---
    float*    Wo   = (float*)ws;                 // 8192 floats = 32KB
    float*    gG   = (float*)(ws + 32768);       // 12 x 4096 floats
    float*    gT   = gG  + 4096;
    float*    gA   = gT  + 4096;
    float*    gAn  = gA  + 4096;
    float*    gA0  = gAn + 4096;
    float*    gP   = gA0 + 4096;
    float*    gPn  = gP  + 4096;
    float*    gB0  = gPn + 4096;
    float*    gB1  = gB0 + 4096;
    float*    gB2  = gB1 + 4096;
    float*    gB3  = gB2 + 4096;
    float*    gB4  = gB3 + 4096;
    float*    gSc  = gB4 + 4096;                 // 2 floats (pad to 64)
    // --- big arrays ---
    float*          d_e2m    = gSc + 64;               // n
    float*          d_e3p    = d_e2m + n;              // n
    float*          gso2     = d_e3p + n;              // n
    unsigned short* xwb      = (unsigned short*)(gso2 + n);       // n*64 bf16
    unsigned*       gcur     = (unsigned*)(xwb + (size_t)n * DOUT); // nbk+8
    uintptr_t bb_ = ((uintptr_t)(gcur + nbk + 8) + 15) & ~(uintptr_t)15;
    unsigned*       bucketed = (unsigned*)bb_;                     // nbk*REGION u32
    uint2*          spill    = (uint2*)(bucketed + (size_t)nbk * REGION); // nbk*REGION u2

    // ---- Bjorck chain: 14 small multi-block dispatches ----------------------
    gram_pass<<<8, 256, 0, stream>>>(W, gG);                              // G
    mm_pass<<<8, 256, 0, stream>>>(gG, nullptr, gG, gT, nullptr, nullptr); // H = G^2
    mm_pass<<<8, 256, 0, stream>>>(gT, nullptr, gT, gA, nullptr, nullptr); // H2 = G^4
    power_prep<<<1, 256, 0, stream>>>(gA, gG, gSc, gA0, gB0);             // sc,rs,A0,B0
    mm_pass<<<8, 256, 0, stream>>>(gA0, nullptr, gB0, gT, nullptr, nullptr); // T = A0@B0
    mm_pass<<<8, 256, 0, stream>>>(gT, nullptr, gB0, gA, nullptr, gB1);   // A1 (+B1)
    mm_pass<<<16, 256, 0, stream>>>(gB0, gA, gB1, gP, gT, nullptr);       // P=B0B1, T=A1B1
    mm_pass<<<8, 256, 0, stream>>>(gT, nullptr, gB1, gAn, nullptr, gB2);  // A2 (+B2)
    mm_pass<<<16, 256, 0, stream>>>(gP, gAn, gB2, gPn, gT, nullptr);      // P=PB2, T=A2B2
    mm_pass<<<8, 256, 0, stream>>>(gT, nullptr, gB2, gA, nullptr, gB3);   // A3 (+B3)
    mm_pass<<<16, 256, 0, stream>>>(gPn, gA, gB3, gP, gT, nullptr);       // P=PB3, T=A3B3
    mm_pass<<<8, 256, 0, stream>>>(gT, nullptr, gB3, gAn, nullptr, gB4);  // A4 (+B4)
    mm_pass<<<8, 256, 0, stream>>>(gP, nullptr, gB4, gPn, nullptr, nullptr); // P final
    wo_pass<<<8, 256, 0, stream>>>(W, gPn, gSc, Wo);                      // Wo

    // ---- node prep (+ gcur init) + feature transform -----------------------
    node_prep<<<(n + 255) / 256, 256, 0, stream>>>(diags, m1, m2, m3, e1, e2, e3,
                                                   d_e2m, d_e3p, gso2, gcur, nbk, n);
    xw_kernel<<<(n + XN - 1) / XN, 256, 0, stream>>>(x, Wo, xwb, n);
    // ---- fused binning (1024 threads, int4 MLP) -----------------------------
    bin_scatter<<<NBLK, 1024, 0, stream>>>(ei, gcur, bucketed, e_cnt, chunk, nbk);
    // ---- fused per-bucket CSR sort + gather + softmax -----------------------
    csr_gather<<<nbk, 512, 0, stream>>>(bucketed, gcur, d_e2m, d_e3p,
                                        xwb, gso2, b, spill, out, n);
}